// Round 1
// baseline (802.497 us; speedup 1.0000x reference)
//
#include <hip/hip_runtime.h>
#include <stdint.h>
#include <stddef.h>

// Problem constants
#define T_TOK 2048     // B*S tokens
#define DMODEL 1024
#define NHEAD 16
#define HDIM 64
#define NEXP 8
#define FDIM 4096
#define SLEN 1024
#define NBATCH 2
#define LN_EPS 1e-5f

typedef unsigned short u16;
typedef __attribute__((ext_vector_type(8))) short s16x8;   // 8 bf16 MFMA frag
typedef __attribute__((ext_vector_type(4))) float f32x4;   // MFMA accumulator
typedef __attribute__((ext_vector_type(4))) unsigned short u16x4;
typedef __attribute__((ext_vector_type(8))) unsigned short u16x8;

typedef __attribute__((address_space(1))) void gvoid;      // global
typedef __attribute__((address_space(3))) void lvoid;      // LDS

__device__ __forceinline__ u16 f2bf(float x) {
  union { float f; unsigned int u; } v; v.f = x;
  unsigned int r = v.u + 0x7fffu + ((v.u >> 16) & 1u);  // RNE
  return (u16)(r >> 16);
}

// async global->LDS, 16B/lane. Dest is wave-uniform base; HW adds lane*16.
__device__ __forceinline__ void gl_lds16(const u16* g, u16* lds_base) {
  __builtin_amdgcn_global_load_lds((gvoid*)g, (lvoid*)lds_base, 16, 0, 0);
}

// ---------------------------------------------------------------------------
// fp32 -> bf16 convert (named clones for profile attribution)
// ---------------------------------------------------------------------------
__device__ __forceinline__ void cvt_body(const float* __restrict__ x,
                                         u16* __restrict__ y, long n4) {
  long i = (long)blockIdx.x * 256 + threadIdx.x;
  if (i >= n4) return;
  float4 v = ((const float4*)x)[i];
  u16x4 o;
  o[0] = f2bf(v.x); o[1] = f2bf(v.y); o[2] = f2bf(v.z); o[3] = f2bf(v.w);
  ((u16x4*)y)[i] = o;
}
__global__ __launch_bounds__(256) void cvt_small(const float* x, u16* y, long n4) { cvt_body(x, y, n4); }
__global__ __launch_bounds__(256) void cvt_w1(const float* x, u16* y, long n4) { cvt_body(x, y, n4); }
__global__ __launch_bounds__(256) void cvt_w2(const float* x, u16* y, long n4) { cvt_body(x, y, n4); }

// ---------------------------------------------------------------------------
// Pipelined GEMM body: C = act(A @ B^T + bias), BN=128, BM in {64,128}.
// Double-buffered LDS, prefetch distance 2, raw s_barrier + partial vmcnt
// waits (never vmcnt(0) mid-loop) so tile k+1's DMA stays in flight while
// tile k is computed.
// ---------------------------------------------------------------------------
template<int BM, int OUTBF, int DOGELU>
__device__ __forceinline__ void gemm_body(
    const u16* __restrict__ A, long lda,
    const u16* __restrict__ Bp, long ldb,
    char* __restrict__ C, long ldc,
    const float* __restrict__ bias,
    int Mloc, int k0start, int Kc, int m0, int n0) {
  __shared__ u16 As[2][BM][64];
  __shared__ u16 Bs[2][128][64];
  constexpr int SM = BM / 32;           // M-frags per wave
  constexpr int LPI = BM / 32 + 4;      // gl_lds insts per wave per tile

  int tid = threadIdx.x;
  int lane = tid & 63, w = tid >> 6;
  int lrow = lane >> 3;                 // 0..7
  int sg8 = ((lane & 7) ^ lrow) * 8;    // XOR-swizzled source granule
  int q = lane >> 4, rr = lane & 15;
  int wm = (w & 1) * (BM / 2), wn = (w >> 1) * 64;
  int NIT = Kc >> 6;

  auto issue = [&](int kt, int b) {
    int k0 = k0start + (kt << 6);
    for (int p = 0; p < BM / 32; p++) {
      int rb = p * 32 + w * 8;
      int gr = m0 + rb + lrow; if (gr > Mloc - 1) gr = Mloc - 1;   // M-tail clamp
      gl_lds16(A + (long)gr * lda + k0 + sg8, &As[b][rb][0]);
    }
    for (int p = 0; p < 4; p++) {
      int rb = p * 32 + w * 8;
      gl_lds16(Bp + (long)(n0 + rb + lrow) * ldb + k0 + sg8, &Bs[b][rb][0]);
    }
  };

  f32x4 acc[SM][4];
  for (int i = 0; i < SM; i++)
    for (int j = 0; j < 4; j++)
      for (int r = 0; r < 4; r++) acc[i][j][r] = 0.f;

  issue(0, 0);
  if (NIT > 1) issue(1, 1);

  int slot0 = ((q ^ (rr & 7)) * 8);           // kk=0 swizzled slot
  int slot1 = (((4 + q) ^ (rr & 7)) * 8);     // kk=1

  for (int kt = 0; kt < NIT; kt++) {
    int b = kt & 1;
    // wait for tile kt only; tile kt+1's LPI loads remain outstanding
    if (kt + 1 < NIT)
      asm volatile("s_waitcnt vmcnt(%0)" :: "i"(LPI) : "memory");
    else
      asm volatile("s_waitcnt vmcnt(0)" ::: "memory");
    asm volatile("s_barrier" ::: "memory");

    s16x8 a0[SM], a1[SM], b0[4], b1[4];
    for (int i = 0; i < SM; i++) {
      a0[i] = *(const s16x8*)&As[b][wm + i * 16 + rr][slot0];
      a1[i] = *(const s16x8*)&As[b][wm + i * 16 + rr][slot1];
    }
    for (int j = 0; j < 4; j++) {
      b0[j] = *(const s16x8*)&Bs[b][wn + j * 16 + rr][slot0];
      b1[j] = *(const s16x8*)&Bs[b][wn + j * 16 + rr][slot1];
    }
    asm volatile("s_waitcnt lgkmcnt(0)" ::: "memory");  // frags in regs
    asm volatile("s_barrier" ::: "memory");             // all waves done reading buf b
    if (kt + 2 < NIT) issue(kt + 2, b);                 // overwrite buf b (visible at kt+2)

    for (int i = 0; i < SM; i++)
      for (int j = 0; j < 4; j++) {
        acc[i][j] = __builtin_amdgcn_mfma_f32_16x16x32_bf16(a0[i], b0[j], acc[i][j], 0, 0, 0);
        acc[i][j] = __builtin_amdgcn_mfma_f32_16x16x32_bf16(a1[i], b1[j], acc[i][j], 0, 0, 0);
      }
  }

  for (int i = 0; i < SM; i++) {
    for (int j = 0; j < 4; j++) {
      int col = n0 + wn + j * 16 + rr;
      float bv = bias ? bias[col] : 0.f;
      for (int r = 0; r < 4; r++) {
        int row = m0 + wm + i * 16 + q * 4 + r;
        if (row < Mloc) {
          float v = acc[i][j][r] + bv;
          if (DOGELU) v = 0.5f * v * (1.f + erff(v * 0.70710678118f));
          if (OUTBF) ((u16*)C)[(long)row * ldc + col] = f2bf(v);
          else ((float*)C)[(long)row * ldc + col] = v;
        }
      }
    }
  }
}

// ---- named GEMM wrappers (1-D grids, XCD-chunked work decode) -------------
// HW maps hardware block id h -> XCD (h % 8). Bijective remap (m204 form,
// nwg % 8 == 0): work = (h%8)*(nwg/8) + h/8 gives each XCD one contiguous
// chunk of the work space. Inside a chunk, y varies fastest so blocks that
// share a B-panel are launched back-to-back (panel stays in that XCD's L2),
// and the handful of active A-panels cycle within a resident window.

// QKV projection: work space = 24 n-tiles x 32 m-tiles = 768
__global__ __launch_bounds__(256) void k_qkv(const u16* __restrict__ A,
                                             const u16* __restrict__ B,
                                             u16* __restrict__ C,
                                             const float* __restrict__ bias) {
  int h = blockIdx.x;
  int work = (h & 7) * 96 + (h >> 3);
  int x = work / 32, y = work % 32;          // per XCD: 3 n-panels, all m
  gemm_body<64, 1, 0>(A, DMODEL, B, DMODEL, (char*)C, 3 * DMODEL, bias,
                      T_TOK, 0, DMODEL, y * 64, x * 128);
}

// out-projection, split-K=2: work space = 8 x * 32 y * 2 z = 512
__global__ __launch_bounds__(256) void k_outp(const u16* __restrict__ A,
                                              const u16* __restrict__ B,
                                              float* __restrict__ Cpart) {
  int h = blockIdx.x;
  int work = (h & 7) * 64 + (h >> 3);
  int y = work % 32;
  int combo = work / 32;                     // 0..15 = (z<<3)|x
  int x = combo & 7, z = combo >> 3;
  char* C = (char*)(Cpart + (long)z * T_TOK * DMODEL);
  gemm_body<64, 0, 0>(A, DMODEL, B, DMODEL, C, DMODEL, nullptr,
                      T_TOK, z * 512, 512, y * 64, x * 128);
}

// FFN1: work space = 8 experts * 32 n-tiles * 16 m-tiles = 4096
// chunk size 512 == one expert -> each XCD owns exactly one expert's GEMM;
// w1[z] panels and the ~1MB of active x-rows become L2-resident.
__global__ __launch_bounds__(256) void k_ffn1(const u16* __restrict__ Ag,
                                              const u16* __restrict__ Bg,
                                              u16* __restrict__ Cg,
                                              const float* __restrict__ biasg,
                                              const int* __restrict__ cntp,
                                              const int* __restrict__ offp) {
  int hh = blockIdx.x;
  int work = (hh & 7) * 512 + (hh >> 3);
  int z = work >> 9;
  int w2 = work & 511;
  int x = w2 >> 4, y = w2 & 15;              // y fastest: B-panel reuse in L2
  int Mloc = cntp[z];
  int m0 = y * 128;
  if (m0 >= Mloc) return;
  long o = offp[z];
  gemm_body<128, 1, 1>(Ag + o * DMODEL, DMODEL,
                       Bg + (long)z * FDIM * DMODEL, DMODEL,
                       (char*)(Cg + o * FDIM), FDIM,
                       biasg + (long)z * FDIM,
                       Mloc, 0, DMODEL, m0, x * 128);
}

// FFN2: work space = 8 experts * 8 n-tiles * 32 m-tiles = 2048, one expert/XCD
__global__ __launch_bounds__(256) void k_ffn2(const u16* __restrict__ Ag,
                                              const u16* __restrict__ Bg,
                                              float* __restrict__ Cg,
                                              const float* __restrict__ biasg,
                                              const int* __restrict__ cntp,
                                              const int* __restrict__ offp) {
  int hh = blockIdx.x;
  int work = (hh & 7) * 256 + (hh >> 3);
  int z = work >> 8;
  int w2 = work & 255;
  int x = w2 >> 5, y = w2 & 31;              // y fastest: B-panel reuse in L2
  int Mloc = cntp[z];
  int m0 = y * 64;
  if (m0 >= Mloc) return;
  long o = offp[z];
  gemm_body<64, 0, 0>(Ag + o * FDIM, FDIM,
                      Bg + (long)z * DMODEL * FDIM, FDIM,
                      (char*)(Cg + o * DMODEL), DMODEL,
                      biasg + (long)z * DMODEL,
                      Mloc, 0, FDIM, m0, x * 128);
}

// ---------------------------------------------------------------------------
// V part of qkv -> Vt (B,H,HD,S) bf16 (transposed via LDS tile)
// ---------------------------------------------------------------------------
__global__ __launch_bounds__(256) void transpose_v(const u16* __restrict__ qkv,
                                                   u16* __restrict__ vt) {
  __shared__ u16 tile[64][65];
  int s0 = blockIdx.x * 64, bh = blockIdx.y;
  int b = bh >> 4, h = bh & 15;
  int r = threadIdx.x >> 3, c = (threadIdx.x & 7) * 8;
  for (int p = 0; p < 64; p += 32) {
    u16x8 v = *(const u16x8*)&qkv[(long)(b * SLEN + s0 + p + r) * 3072 + 2048 + h * 64 + c];
    for (int j = 0; j < 8; j++) tile[p + r][c + j] = v[j];
  }
  __syncthreads();
  for (int p = 0; p < 64; p += 32) {
    int d = p + r;
    u16x8 v;
    for (int j = 0; j < 8; j++) v[j] = tile[c + j][d];
    *(u16x8*)&vt[((long)bh * 64 + d) * SLEN + s0 + c] = v;
  }
}

// ---------------------------------------------------------------------------
// Fused flash attention: per (q-tile 128, b*h) block. Writes (B,S,D) bf16.
// 1-D grid of 256; all 8 q-tiles of a head land on the same XCD so the
// head's K/V stream is L2-resident.
// ---------------------------------------------------------------------------
__global__ __launch_bounds__(256) void fused_attn(const u16* __restrict__ qkv,
                                                  const u16* __restrict__ vt,
                                                  u16* __restrict__ o2) {
  __shared__ u16 Qs[128][64];   // swizzled
  __shared__ u16 Ks[64][64];    // swizzled
  __shared__ u16 Vs[64][64];    // swizzled (rows = head-dim d, cols = 64 keys)
  __shared__ u16 Ps[128][72];   // padded

  int hh = blockIdx.x;
  int work = (hh & 7) * 32 + (hh >> 3);
  int bh = work >> 3, qt = work & 7;
  int b = bh >> 4, h = bh & 15;
  const u16* base = qkv + (long)b * SLEN * 3072 + h * 64;
  const u16* vbase = vt + (long)bh * HDIM * SLEN;

  int tid = threadIdx.x, lane = tid & 63, w = tid >> 6;
  int lrow = lane >> 3;
  int sg8 = ((lane & 7) ^ lrow) * 8;
  int q = lane >> 4, rr = lane & 15;
  int wm = w * 32;

  // stage Q once
  for (int p = 0; p < 4; p++) {
    int rb = p * 32 + w * 8;
    gl_lds16(base + (long)(qt * 128 + rb + lrow) * 3072 + sg8, &Qs[rb][0]);
  }

  f32x4 O[2][4];
  float mi[2][4], li[2][4];
  for (int i = 0; i < 2; i++)
    for (int r = 0; r < 4; r++) { mi[i][r] = -1e30f; li[i][r] = 0.f; }
  for (int i = 0; i < 2; i++)
    for (int jn = 0; jn < 4; jn++)
      for (int r = 0; r < 4; r++) O[i][jn][r] = 0.f;

  for (int kt = 0; kt < 16; kt++) {
    __syncthreads();
    for (int p = 0; p < 2; p++) {
      int rb = p * 32 + w * 8;
      gl_lds16(base + (long)(kt * 64 + rb + lrow) * 3072 + 1024 + sg8, &Ks[rb][0]);
      gl_lds16(vbase + (long)(rb + lrow) * SLEN + kt * 64 + sg8, &Vs[rb][0]);
    }
    __syncthreads();

    // S = Q @ K^T
    f32x4 S[2][4];
    for (int i = 0; i < 2; i++)
      for (int j = 0; j < 4; j++)
        for (int r = 0; r < 4; r++) S[i][j][r] = 0.f;
    for (int ks = 0; ks < 2; ks++) {
      int slot = (((ks * 4 + q) ^ (rr & 7)) * 8);
      s16x8 aq0 = *(const s16x8*)&Qs[wm + rr][slot];
      s16x8 aq1 = *(const s16x8*)&Qs[wm + 16 + rr][slot];
      for (int j = 0; j < 4; j++) {
        s16x8 bk = *(const s16x8*)&Ks[j * 16 + rr][slot];
        S[0][j] = __builtin_amdgcn_mfma_f32_16x16x32_bf16(aq0, bk, S[0][j], 0, 0, 0);
        S[1][j] = __builtin_amdgcn_mfma_f32_16x16x32_bf16(aq1, bk, S[1][j], 0, 0, 0);
      }
    }

    // online softmax
    for (int i = 0; i < 2; i++) {
      for (int r = 0; r < 4; r++) {
        float mx = -1e30f;
        for (int j = 0; j < 4; j++) mx = fmaxf(mx, S[i][j][r]);
        for (int o = 1; o < 16; o <<= 1) mx = fmaxf(mx, __shfl_xor(mx, o));
        mx *= 0.125f;
        float mnew = fmaxf(mi[i][r], mx);
        float al = __expf(mi[i][r] - mnew);
        mi[i][r] = mnew;
        float ps = 0.f;
        for (int j = 0; j < 4; j++) {
          float e = __expf(S[i][j][r] * 0.125f - mnew);
          S[i][j][r] = e;
          ps += e;
        }
        for (int o = 1; o < 16; o <<= 1) ps += __shfl_xor(ps, o);
        li[i][r] = li[i][r] * al + ps;
        for (int jn = 0; jn < 4; jn++) O[i][jn][r] *= al;
      }
    }

    // P -> LDS (C-layout scatter)
    for (int i = 0; i < 2; i++)
      for (int j = 0; j < 4; j++)
        for (int r = 0; r < 4; r++)
          Ps[wm + i * 16 + q * 4 + r][j * 16 + rr] = f2bf(S[i][j][r]);
    __syncthreads();

    // O += P @ V
    for (int ks = 0; ks < 2; ks++) {
      s16x8 ap0 = *(const s16x8*)&Ps[wm + rr][ks * 32 + q * 8];
      s16x8 ap1 = *(const s16x8*)&Ps[wm + 16 + rr][ks * 32 + q * 8];
      int slot = (((ks * 4 + q) ^ (rr & 7)) * 8);
      for (int jn = 0; jn < 4; jn++) {
        s16x8 bv = *(const s16x8*)&Vs[jn * 16 + rr][slot];
        O[0][jn] = __builtin_amdgcn_mfma_f32_16x16x32_bf16(ap0, bv, O[0][jn], 0, 0, 0);
        O[1][jn] = __builtin_amdgcn_mfma_f32_16x16x32_bf16(ap1, bv, O[1][jn], 0, 0, 0);
      }
    }
  }

  for (int i = 0; i < 2; i++)
    for (int r = 0; r < 4; r++) {
      float inv = 1.f / li[i][r];
      int s = qt * 128 + wm + i * 16 + q * 4 + r;
      long rowp = ((long)(b * SLEN + s)) * DMODEL + h * 64;
      for (int jn = 0; jn < 4; jn++)
        o2[rowp + jn * 16 + rr] = f2bf(O[i][jn][r] * inv);
    }
}

// ---------------------------------------------------------------------------
// residual add (+out-proj bias, 2 split-K partials) + LayerNorm -> fp32+bf16
// ---------------------------------------------------------------------------
__global__ __launch_bounds__(256) void add_ln(const float* __restrict__ a,
                                              const float* __restrict__ p0,
                                              const float* __restrict__ p1,
                                              const float* __restrict__ ob,
                                              const float* __restrict__ g,
                                              const float* __restrict__ bb,
                                              float* __restrict__ xf, u16* __restrict__ xb) {
  int t = blockIdx.x, tid = threadIdx.x;
  float4 va = ((const float4*)(a + (long)t * DMODEL))[tid];
  float4 v0v = ((const float4*)(p0 + (long)t * DMODEL))[tid];
  float4 v1v = ((const float4*)(p1 + (long)t * DMODEL))[tid];
  float4 vo = ((const float4*)ob)[tid];
  float v0 = va.x + v0v.x + v1v.x + vo.x;
  float v1 = va.y + v0v.y + v1v.y + vo.y;
  float v2 = va.z + v0v.z + v1v.z + vo.z;
  float v3 = va.w + v0v.w + v1v.w + vo.w;
  float s = v0 + v1 + v2 + v3;
  float s2 = v0 * v0 + v1 * v1 + v2 * v2 + v3 * v3;
  __shared__ float sa[4], sb[4];
  for (int o = 32; o; o >>= 1) { s += __shfl_down(s, o); s2 += __shfl_down(s2, o); }
  int lane = tid & 63, w = tid >> 6;
  if (lane == 0) { sa[w] = s; sb[w] = s2; }
  __syncthreads();
  s = sa[0] + sa[1] + sa[2] + sa[3];
  s2 = sb[0] + sb[1] + sb[2] + sb[3];
  float mu = s * (1.f / DMODEL);
  float var = s2 * (1.f / DMODEL) - mu * mu;
  float rs = rsqrtf(var + LN_EPS);
  float4 gg = ((const float4*)g)[tid];
  float4 bv = ((const float4*)bb)[tid];
  float4 o;
  o.x = (v0 - mu) * rs * gg.x + bv.x;
  o.y = (v1 - mu) * rs * gg.y + bv.y;
  o.z = (v2 - mu) * rs * gg.z + bv.z;
  o.w = (v3 - mu) * rs * gg.w + bv.w;
  ((float4*)(xf + (long)t * DMODEL))[tid] = o;
  u16x4 obv;
  obv[0] = f2bf(o.x); obv[1] = f2bf(o.y); obv[2] = f2bf(o.z); obv[3] = f2bf(o.w);
  ((u16x4*)(xb + (long)t * DMODEL))[tid] = obv;
}

// ---------------------------------------------------------------------------
// Gate: logits, full softmax (usage/aux), top-2 routing lists
// ---------------------------------------------------------------------------
__global__ __launch_bounds__(256) void gate_kernel(
    const float* __restrict__ xf, const float* __restrict__ gw, const float* __restrict__ gb,
    int* __restrict__ cnt, int* __restrict__ tok_list,
    int* __restrict__ tk_e, int* __restrict__ tk_pos, float* __restrict__ tk_prob,
    float* __restrict__ usage) {
  int wid = threadIdx.x >> 6, lane = threadIdx.x & 63;
  int t = blockIdx.x * 4 + wid;
  float xv[16];
  for (int j = 0; j < 16; j++) xv[j] = xf[(long)t * DMODEL + j * 64 + lane];
  float l[8];
  for (int e = 0; e < 8; e++) {
    float d = 0.f;
    for (int j = 0; j < 16; j++) d += xv[j] * gw[e * DMODEL + j * 64 + lane];
    for (int o = 32; o; o >>= 1) d += __shfl_down(d, o);
    l[e] = d;  // valid on lane 0 only
  }
  __shared__ float us[8];
  if (threadIdx.x < 8) us[threadIdx.x] = 0.f;
  __syncthreads();
  if (lane == 0) {
    float mx = -1e30f;
    for (int e = 0; e < 8; e++) { l[e] += gb[e]; mx = fmaxf(mx, l[e]); }
    float ex[8], sum = 0.f;
    for (int e = 0; e < 8; e++) { ex[e] = expf(l[e] - mx); sum += ex[e]; }
    float inv = 1.f / sum;
    for (int e = 0; e < 8; e++) atomicAdd(&us[e], ex[e] * inv);
    int i1 = 0;
    for (int e = 1; e < 8; e++) if (l[e] > l[i1]) i1 = e;
    int i2 = (i1 == 0) ? 1 : 0;
    for (int e = 0; e < 8; e++) if (e != i1 && l[e] > l[i2]) i2 = e;
    float bb = expf(l[i2] - l[i1]);
    float p1 = 1.f / (1.f + bb), p2 = bb / (1.f + bb);
    int pos1 = atomicAdd(&cnt[i1], 1);
    tok_list[i1 * 2048 + pos1] = t;
    tk_e[2 * t] = i1; tk_pos[2 * t] = pos1; tk_prob[2 * t] = p1;
    int pos2 = atomicAdd(&cnt[i2], 1);
    tok_list[i2 * 2048 + pos2] = t;
    tk_e[2 * t + 1] = i2; tk_pos[2 * t + 1] = pos2; tk_prob[2 * t + 1] = p2;
  }
  __syncthreads();
  if (threadIdx.x < 8) atomicAdd(&usage[threadIdx.x], us[threadIdx.x]);
}

__global__ void finalize_gate(const int* __restrict__ cnt, int* __restrict__ offp,
                              const float* __restrict__ usage, float* __restrict__ aux_out) {
  if (threadIdx.x == 0) {
    int o = 0;
    for (int e = 0; e < 8; e++) { offp[e] = o; o += cnt[e]; }
    float s = 0.f;
    for (int e = 0; e < 8; e++) { float u = usage[e] * (1.f / T_TOK); s += u * u; }
    aux_out[0] = (float)NEXP * s;
  }
}

// gather x rows per expert into compact buffer
__global__ __launch_bounds__(256) void gather_x(const u16* __restrict__ xb,
                                                const int* __restrict__ cnt,
                                                const int* __restrict__ offp,
                                                const int* __restrict__ tok_list,
                                                u16* __restrict__ xg) {
  int e = blockIdx.y, i = blockIdx.x;
  if (i >= cnt[e]) return;
  int t = tok_list[e * 2048 + i];
  long j = offp[e] + i;
  ((uint2*)(xg + j * DMODEL))[threadIdx.x] =
      ((const uint2*)(xb + (long)t * DMODEL))[threadIdx.x];
}

// weighted expert-output combine + residual + LN2 -> final output
__global__ __launch_bounds__(256) void moe_ln2(
    const float* __restrict__ xf, const float* __restrict__ y,
    const int* __restrict__ offp, const int* __restrict__ tk_e,
    const int* __restrict__ tk_pos, const float* __restrict__ tk_prob,
    const float* __restrict__ g, const float* __restrict__ bb, float* __restrict__ out) {
  int t = blockIdx.x, tid = threadIdx.x;
  int e0 = tk_e[2 * t], e1 = tk_e[2 * t + 1];
  long j0 = (long)offp[e0] + tk_pos[2 * t];
  long j1 = (long)offp[e1] + tk_pos[2 * t + 1];
  float p0 = tk_prob[2 * t], p1 = tk_prob[2 * t + 1];
  float4 vx = ((const float4*)(xf + (long)t * DMODEL))[tid];
  float4 y0 = ((const float4*)(y + j0 * DMODEL))[tid];
  float4 y1 = ((const float4*)(y + j1 * DMODEL))[tid];
  float v0 = vx.x + p0 * y0.x + p1 * y1.x;
  float v1 = vx.y + p0 * y0.y + p1 * y1.y;
  float v2 = vx.z + p0 * y0.z + p1 * y1.z;
  float v3 = vx.w + p0 * y0.w + p1 * y1.w;
  float s = v0 + v1 + v2 + v3;
  float s2 = v0 * v0 + v1 * v1 + v2 * v2 + v3 * v3;
  __shared__ float sa[4], sb[4];
  for (int o = 32; o; o >>= 1) { s += __shfl_down(s, o); s2 += __shfl_down(s2, o); }
  int lane = tid & 63, w = tid >> 6;
  if (lane == 0) { sa[w] = s; sb[w] = s2; }
  __syncthreads();
  s = sa[0] + sa[1] + sa[2] + sa[3];
  s2 = sb[0] + sb[1] + sb[2] + sb[3];
  float mu = s * (1.f / DMODEL);
  float var = s2 * (1.f / DMODEL) - mu * mu;
  float rs = rsqrtf(var + LN_EPS);
  float4 gg = ((const float4*)g)[tid];
  float4 bv = ((const float4*)bb)[tid];
  float4 o;
  o.x = (v0 - mu) * rs * gg.x + bv.x;
  o.y = (v1 - mu) * rs * gg.y + bv.y;
  o.z = (v2 - mu) * rs * gg.z + bv.z;
  o.w = (v3 - mu) * rs * gg.w + bv.w;
  ((float4*)(out + (long)t * DMODEL))[tid] = o;
}

// ---------------------------------------------------------------------------
extern "C" void kernel_launch(void* const* d_in, const int* in_sizes, int n_in,
                              void* d_out, int out_size, void* d_ws, size_t ws_size,
                              hipStream_t stream) {
  const float* src  = (const float*)d_in[0];
  const float* inw  = (const float*)d_in[1];
  const float* inb  = (const float*)d_in[2];
  const float* outw = (const float*)d_in[3];
  const float* outb = (const float*)d_in[4];
  const float* gw   = (const float*)d_in[5];
  const float* gb   = (const float*)d_in[6];
  const float* w1   = (const float*)d_in[7];
  const float* b1   = (const float*)d_in[8];
  const float* w2   = (const float*)d_in[9];
  const float* b2   = (const float*)d_in[10];
  const float* g1   = (const float*)d_in[11];
  const float* bb1  = (const float*)d_in[12];
  const float* g2   = (const float*)d_in[13];
  const float* bb2  = (const float*)d_in[14];
  float* out = (float*)d_out;

  char* w = (char*)d_ws;
  auto alloc = [&](size_t bytes) {
    char* p = w;
    w += (bytes + 255) & ~(size_t)255;
    return p;
  };

  int*   cnt     = (int*)alloc(8 * 4);
  int*   offp    = (int*)alloc(8 * 4);
  float* usage   = (float*)alloc(8 * 4);
  int*   tok_list= (int*)alloc((size_t)NEXP * 2048 * 4);
  int*   tk_e    = (int*)alloc((size_t)2 * T_TOK * 4);
  int*   tk_pos  = (int*)alloc((size_t)2 * T_TOK * 4);
  float* tk_prob = (float*)alloc((size_t)2 * T_TOK * 4);

  u16* src_bf  = (u16*)alloc((size_t)T_TOK * DMODEL * 2);
  u16* inw_bf  = (u16*)alloc((size_t)3 * DMODEL * DMODEL * 2);
  u16* outw_bf = (u16*)alloc((size_t)DMODEL * DMODEL * 2);
  u16* w1_bf   = (u16*)alloc((size_t)NEXP * FDIM * DMODEL * 2);
  u16* w2_bf   = (u16*)alloc((size_t)NEXP * DMODEL * FDIM * 2);
  u16* qkv_bf  = (u16*)alloc((size_t)T_TOK * 3 * DMODEL * 2);
  u16* vt_bf   = (u16*)alloc((size_t)T_TOK * DMODEL * 2);    // (B,H,HD,S)
  u16* o2_bf   = (u16*)alloc((size_t)T_TOK * DMODEL * 2);    // (B,S,D)
  float* attn_p= (float*)alloc((size_t)2 * T_TOK * DMODEL * 4);  // 2 split-K partials
  float* x_f   = (float*)alloc((size_t)T_TOK * DMODEL * 4);
  u16* x_bf    = (u16*)alloc((size_t)T_TOK * DMODEL * 2);
  u16* xg_bf   = (u16*)alloc((size_t)2 * T_TOK * DMODEL * 2);
  u16* h_bf    = (u16*)alloc((size_t)2 * T_TOK * FDIM * 2);
  float* y_f   = (float*)alloc((size_t)2 * T_TOK * DMODEL * 4);
  (void)ws_size; (void)n_in; (void)in_sizes; (void)out_size;

  hipMemsetAsync(cnt, 0, 3 * 256, stream);  // cnt, offp, usage regions

  // bf16 conversions
  cvt_small<<<(T_TOK * DMODEL / 4 + 255) / 256, 256, 0, stream>>>(src, src_bf, T_TOK * DMODEL / 4);
  cvt_small<<<(3 * DMODEL * DMODEL / 4 + 255) / 256, 256, 0, stream>>>(inw, inw_bf, 3L * DMODEL * DMODEL / 4);
  cvt_small<<<(DMODEL * DMODEL / 4 + 255) / 256, 256, 0, stream>>>(outw, outw_bf, (long)DMODEL * DMODEL / 4);
  cvt_w1<<<(int)((long)NEXP * FDIM * DMODEL / 4 / 256), 256, 0, stream>>>(w1, w1_bf, (long)NEXP * FDIM * DMODEL / 4);
  cvt_w2<<<(int)((long)NEXP * DMODEL * FDIM / 4 / 256), 256, 0, stream>>>(w2, w2_bf, (long)NEXP * DMODEL * FDIM / 4);

  // QKV projection: (2048x1024) @ (3072x1024)^T + b -> bf16  (768 work items)
  k_qkv<<<768, 256, 0, stream>>>(src_bf, inw_bf, qkv_bf, inb);

  transpose_v<<<dim3(16, 32), 256, 0, stream>>>(qkv_bf, vt_bf);

  // fused flash attention -> o2_bf (B,S,D)  (256 work items, head-per-XCD)
  fused_attn<<<256, 256, 0, stream>>>(qkv_bf, vt_bf, o2_bf);

  // output projection, split-K=2 -> two fp32 partials (bias folded into add_ln)
  k_outp<<<512, 256, 0, stream>>>(o2_bf, outw_bf, attn_p);

  // residual + out-proj bias + LN1
  add_ln<<<T_TOK, 256, 0, stream>>>(src, attn_p, attn_p + (long)T_TOK * DMODEL,
                                    outb, g1, bb1, x_f, x_bf);

  // gate + routing
  gate_kernel<<<T_TOK / 4, 256, 0, stream>>>(x_f, gw, gb, cnt, tok_list,
                                             tk_e, tk_pos, tk_prob, usage);
  finalize_gate<<<1, 64, 0, stream>>>(cnt, offp, usage, out + (long)T_TOK * DMODEL);

  gather_x<<<dim3(2048, 8), 256, 0, stream>>>(x_bf, cnt, offp, tok_list, xg_bf);

  // FFN1 (grouped, gelu fused) -> bf16   (4096 work items, expert-per-XCD)
  k_ffn1<<<4096, 256, 0, stream>>>(xg_bf, w1_bf, h_bf, b1, cnt, offp);

  // FFN2 (grouped) -> fp32               (2048 work items, expert-per-XCD)
  k_ffn2<<<2048, 256, 0, stream>>>(h_bf, w2_bf, y_f, b2, cnt, offp);

  // combine + residual + LN2 -> output
  moe_ln2<<<T_TOK, 256, 0, stream>>>(x_f, y_f, offp, tk_e, tk_pos, tk_prob,
                                     g2, bb2, out);
}

// Round 4
// 672.036 us; speedup vs baseline: 1.1941x; 1.1941x over previous
//
#include <hip/hip_runtime.h>
#include <stdint.h>
#include <stddef.h>

// Problem constants
#define T_TOK 2048     // B*S tokens
#define DMODEL 1024
#define NHEAD 16
#define HDIM 64
#define NEXP 8
#define FDIM 4096
#define SLEN 1024
#define NBATCH 2
#define LN_EPS 1e-5f

typedef unsigned short u16;
typedef __attribute__((ext_vector_type(8))) short s16x8;   // 8 bf16 MFMA frag
typedef __attribute__((ext_vector_type(4))) float f32x4;   // MFMA accumulator
typedef __attribute__((ext_vector_type(4))) unsigned short u16x4;
typedef __attribute__((ext_vector_type(8))) unsigned short u16x8;

typedef __attribute__((address_space(1))) void gvoid;      // global
typedef __attribute__((address_space(3))) void lvoid;      // LDS

__device__ __forceinline__ u16 f2bf(float x) {
  union { float f; unsigned int u; } v; v.f = x;
  unsigned int r = v.u + 0x7fffu + ((v.u >> 16) & 1u);  // RNE
  return (u16)(r >> 16);
}

// async global->LDS, 16B/lane. Dest is wave-uniform base; HW adds lane*16.
__device__ __forceinline__ void gl_lds16(const u16* g, u16* lds_base) {
  __builtin_amdgcn_global_load_lds((gvoid*)g, (lvoid*)lds_base, 16, 0, 0);
}

// ---------------------------------------------------------------------------
// fp32 -> bf16 convert (named clones for profile attribution)
// ---------------------------------------------------------------------------
__device__ __forceinline__ void cvt_body(const float* __restrict__ x,
                                         u16* __restrict__ y, long n4) {
  long i = (long)blockIdx.x * 256 + threadIdx.x;
  if (i >= n4) return;
  float4 v = ((const float4*)x)[i];
  u16x4 o;
  o[0] = f2bf(v.x); o[1] = f2bf(v.y); o[2] = f2bf(v.z); o[3] = f2bf(v.w);
  ((u16x4*)y)[i] = o;
}
__global__ __launch_bounds__(256) void cvt_small(const float* x, u16* y, long n4) { cvt_body(x, y, n4); }
__global__ __launch_bounds__(256) void cvt_w1(const float* x, u16* y, long n4) { cvt_body(x, y, n4); }
__global__ __launch_bounds__(256) void cvt_w2(const float* x, u16* y, long n4) { cvt_body(x, y, n4); }

// ---------------------------------------------------------------------------
// Pipelined GEMM body: C = act(A @ B^T + bias), BN=128, BM in {64,128}.
// Double-buffered LDS, prefetch distance 2, raw s_barrier + partial vmcnt
// waits (never vmcnt(0) mid-loop) so tile k+1's DMA stays in flight while
// tile k is computed.
// Epilogue: restage output tile through LDS (reusing the dead As/Bs buffers)
// so every global store instruction covers full 128B lines — the direct
// per-fragment u16/f32 stores were 32-64B partial-line writes that showed as
// 4-5x WRITE_SIZE amplification (+C-line RMW fetch) in rocprof.
// ---------------------------------------------------------------------------
template<int BM, int OUTBF, int DOGELU>
__device__ __forceinline__ void gemm_body(
    const u16* __restrict__ A, long lda,
    const u16* __restrict__ Bp, long ldb,
    char* __restrict__ C, long ldc,
    const float* __restrict__ bias,
    int Mloc, int k0start, int Kc, int m0, int n0) {
  constexpr int AS_BYTES = 2 * BM * 64 * 2;
  constexpr int SMEM_BYTES = AS_BYTES + 2 * 128 * 64 * 2;   // As + Bs
  __shared__ __align__(16) char smem[SMEM_BYTES];
  u16 (*As)[BM][64]  = reinterpret_cast<u16(*)[BM][64]>(smem);
  u16 (*Bs)[128][64] = reinterpret_cast<u16(*)[128][64]>(smem + AS_BYTES);

  constexpr int SM = BM / 32;           // M-frags per wave
  constexpr int LPI = BM / 32 + 4;      // gl_lds insts per wave per tile

  int tid = threadIdx.x;
  int lane = tid & 63, w = tid >> 6;
  int lrow = lane >> 3;                 // 0..7
  int sg8 = ((lane & 7) ^ lrow) * 8;    // XOR-swizzled source granule
  int q = lane >> 4, rr = lane & 15;
  int wm = (w & 1) * (BM / 2), wn = (w >> 1) * 64;
  int NIT = Kc >> 6;

  auto issue = [&](int kt, int b) {
    int k0 = k0start + (kt << 6);
    for (int p = 0; p < BM / 32; p++) {
      int rb = p * 32 + w * 8;
      int gr = m0 + rb + lrow; if (gr > Mloc - 1) gr = Mloc - 1;   // M-tail clamp
      gl_lds16(A + (long)gr * lda + k0 + sg8, &As[b][rb][0]);
    }
    for (int p = 0; p < 4; p++) {
      int rb = p * 32 + w * 8;
      gl_lds16(Bp + (long)(n0 + rb + lrow) * ldb + k0 + sg8, &Bs[b][rb][0]);
    }
  };

  f32x4 acc[SM][4];
  for (int i = 0; i < SM; i++)
    for (int j = 0; j < 4; j++)
      for (int r = 0; r < 4; r++) acc[i][j][r] = 0.f;

  issue(0, 0);
  if (NIT > 1) issue(1, 1);

  int slot0 = ((q ^ (rr & 7)) * 8);           // kk=0 swizzled slot
  int slot1 = (((4 + q) ^ (rr & 7)) * 8);     // kk=1

  for (int kt = 0; kt < NIT; kt++) {
    int b = kt & 1;
    // wait for tile kt only; tile kt+1's LPI loads remain outstanding
    if (kt + 1 < NIT)
      asm volatile("s_waitcnt vmcnt(%0)" :: "i"(LPI) : "memory");
    else
      asm volatile("s_waitcnt vmcnt(0)" ::: "memory");
    asm volatile("s_barrier" ::: "memory");

    s16x8 a0[SM], a1[SM], b0[4], b1[4];
    for (int i = 0; i < SM; i++) {
      a0[i] = *(const s16x8*)&As[b][wm + i * 16 + rr][slot0];
      a1[i] = *(const s16x8*)&As[b][wm + i * 16 + rr][slot1];
    }
    for (int j = 0; j < 4; j++) {
      b0[j] = *(const s16x8*)&Bs[b][wn + j * 16 + rr][slot0];
      b1[j] = *(const s16x8*)&Bs[b][wn + j * 16 + rr][slot1];
    }
    asm volatile("s_waitcnt lgkmcnt(0)" ::: "memory");  // frags in regs
    asm volatile("s_barrier" ::: "memory");             // all waves done reading buf b
    if (kt + 2 < NIT) issue(kt + 2, b);                 // overwrite buf b (visible at kt+2)

    for (int i = 0; i < SM; i++)
      for (int j = 0; j < 4; j++) {
        acc[i][j] = __builtin_amdgcn_mfma_f32_16x16x32_bf16(a0[i], b0[j], acc[i][j], 0, 0, 0);
        acc[i][j] = __builtin_amdgcn_mfma_f32_16x16x32_bf16(a1[i], b1[j], acc[i][j], 0, 0, 0);
      }
  }

  // ---- epilogue: stage through LDS, then full-line coalesced stores ----
  // Safe to overwrite As/Bs: every wave's ds_reads completed before the last
  // s_barrier (lgkmcnt(0) precedes it); MFMAs consume registers only.
  u16*   Cu = (u16*)smem;     // [BM][128] bf16 tile
  float* Cf = (float*)smem;   // [BM][128] fp32 tile
  for (int i = 0; i < SM; i++)
    for (int j = 0; j < 4; j++) {
      int col = wn + j * 16 + rr;
      float bv = bias ? bias[n0 + col] : 0.f;
      for (int r = 0; r < 4; r++) {
        int row = wm + i * 16 + q * 4 + r;
        float v = acc[i][j][r] + bv;
        if (DOGELU) v = 0.5f * v * (1.f + erff(v * 0.70710678118f));
        if (OUTBF) Cu[row * 128 + col] = f2bf(v);
        else       Cf[row * 128 + col] = v;
      }
    }
  __syncthreads();
  if (OUTBF) {
    for (int p = 0; p < BM / 16; p++) {
      int row = p * 16 + (tid >> 4);
      int co  = (tid & 15) * 8;
      if (m0 + row < Mloc) {
        u16x8 vv = *(const u16x8*)&Cu[row * 128 + co];
        *(u16x8*)((u16*)C + (long)(m0 + row) * ldc + n0 + co) = vv;
      }
    }
  } else {
    for (int p = 0; p < BM / 8; p++) {
      int row = p * 8 + (tid >> 5);
      int co  = (tid & 31) * 4;
      if (m0 + row < Mloc) {
        float4 vv = *(const float4*)&Cf[row * 128 + co];
        *(float4*)((float*)C + (long)(m0 + row) * ldc + n0 + co) = vv;
      }
    }
  }
}

// ---- named GEMM wrappers (R0 grids: balanced round-robin across XCDs) -----
__global__ __launch_bounds__(256) void k_qkv(const u16* __restrict__ A,
                                             const u16* __restrict__ B,
                                             u16* __restrict__ C,
                                             const float* __restrict__ bias) {
  gemm_body<64, 1, 0>(A, DMODEL, B, DMODEL, (char*)C, 3 * DMODEL, bias,
                      T_TOK, 0, DMODEL, blockIdx.y * 64, blockIdx.x * 128);
}

// out-projection, split-K=2: z picks K-half, writes partial buffer z
__global__ __launch_bounds__(256) void k_outp(const u16* __restrict__ A,
                                              const u16* __restrict__ B,
                                              float* __restrict__ Cpart) {
  int z = blockIdx.z;
  char* C = (char*)(Cpart + (long)z * T_TOK * DMODEL);
  gemm_body<64, 0, 0>(A, DMODEL, B, DMODEL, C, DMODEL, nullptr,
                      T_TOK, z * 512, 512, blockIdx.y * 64, blockIdx.x * 128);
}

__global__ __launch_bounds__(256) void k_ffn1(const u16* __restrict__ Ag,
                                              const u16* __restrict__ Bg,
                                              u16* __restrict__ Cg,
                                              const float* __restrict__ biasg,
                                              const int* __restrict__ cntp,
                                              const int* __restrict__ offp) {
  int z = blockIdx.z;
  int Mloc = cntp[z];
  int m0 = blockIdx.y * 128;
  if (m0 >= Mloc) return;
  long o = offp[z];
  gemm_body<128, 1, 1>(Ag + o * DMODEL, DMODEL,
                       Bg + (long)z * FDIM * DMODEL, DMODEL,
                       (char*)(Cg + o * FDIM), FDIM,
                       biasg + (long)z * FDIM,
                       Mloc, 0, DMODEL, m0, blockIdx.x * 128);
}

__global__ __launch_bounds__(256) void k_ffn2(const u16* __restrict__ Ag,
                                              const u16* __restrict__ Bg,
                                              float* __restrict__ Cg,
                                              const float* __restrict__ biasg,
                                              const int* __restrict__ cntp,
                                              const int* __restrict__ offp) {
  int z = blockIdx.z;
  int Mloc = cntp[z];
  int m0 = blockIdx.y * 64;
  if (m0 >= Mloc) return;
  long o = offp[z];
  gemm_body<64, 0, 0>(Ag + o * FDIM, FDIM,
                      Bg + (long)z * DMODEL * FDIM, FDIM,
                      (char*)(Cg + o * DMODEL), DMODEL,
                      biasg + (long)z * DMODEL,
                      Mloc, 0, FDIM, m0, blockIdx.x * 128);
}

// ---------------------------------------------------------------------------
// V part of qkv -> Vt (B,H,HD,S) bf16 (transposed via LDS tile)
// ---------------------------------------------------------------------------
__global__ __launch_bounds__(256) void transpose_v(const u16* __restrict__ qkv,
                                                   u16* __restrict__ vt) {
  __shared__ u16 tile[64][65];
  int s0 = blockIdx.x * 64, bh = blockIdx.y;
  int b = bh >> 4, h = bh & 15;
  int r = threadIdx.x >> 3, c = (threadIdx.x & 7) * 8;
  for (int p = 0; p < 64; p += 32) {
    u16x8 v = *(const u16x8*)&qkv[(long)(b * SLEN + s0 + p + r) * 3072 + 2048 + h * 64 + c];
    for (int j = 0; j < 8; j++) tile[p + r][c + j] = v[j];
  }
  __syncthreads();
  for (int p = 0; p < 64; p += 32) {
    int d = p + r;
    u16x8 v;
    for (int j = 0; j < 8; j++) v[j] = tile[c + j][d];
    *(u16x8*)&vt[((long)bh * 64 + d) * SLEN + s0 + c] = v;
  }
}

// ---------------------------------------------------------------------------
// Fused flash attention: per (q-tile 128, b*h) block. Writes (B,S,D) bf16.
// Output restaged through Ps for full-line stores.
// ---------------------------------------------------------------------------
__global__ __launch_bounds__(256) void fused_attn(const u16* __restrict__ qkv,
                                                  const u16* __restrict__ vt,
                                                  u16* __restrict__ o2) {
  __shared__ u16 Qs[128][64];   // swizzled
  __shared__ u16 Ks[64][64];    // swizzled
  __shared__ u16 Vs[64][64];    // swizzled (rows = head-dim d, cols = 64 keys)
  __shared__ u16 Ps[128][72];   // padded

  int qt = blockIdx.x, bh = blockIdx.y;
  int b = bh >> 4, h = bh & 15;
  const u16* base = qkv + (long)b * SLEN * 3072 + h * 64;
  const u16* vbase = vt + (long)bh * HDIM * SLEN;

  int tid = threadIdx.x, lane = tid & 63, w = tid >> 6;
  int lrow = lane >> 3;
  int sg8 = ((lane & 7) ^ lrow) * 8;
  int q = lane >> 4, rr = lane & 15;
  int wm = w * 32;

  // stage Q once
  for (int p = 0; p < 4; p++) {
    int rb = p * 32 + w * 8;
    gl_lds16(base + (long)(qt * 128 + rb + lrow) * 3072 + sg8, &Qs[rb][0]);
  }

  f32x4 O[2][4];
  float mi[2][4], li[2][4];
  for (int i = 0; i < 2; i++)
    for (int r = 0; r < 4; r++) { mi[i][r] = -1e30f; li[i][r] = 0.f; }
  for (int i = 0; i < 2; i++)
    for (int jn = 0; jn < 4; jn++)
      for (int r = 0; r < 4; r++) O[i][jn][r] = 0.f;

  for (int kt = 0; kt < 16; kt++) {
    __syncthreads();
    for (int p = 0; p < 2; p++) {
      int rb = p * 32 + w * 8;
      gl_lds16(base + (long)(kt * 64 + rb + lrow) * 3072 + 1024 + sg8, &Ks[rb][0]);
      gl_lds16(vbase + (long)(rb + lrow) * SLEN + kt * 64 + sg8, &Vs[rb][0]);
    }
    __syncthreads();

    // S = Q @ K^T
    f32x4 S[2][4];
    for (int i = 0; i < 2; i++)
      for (int j = 0; j < 4; j++)
        for (int r = 0; r < 4; r++) S[i][j][r] = 0.f;
    for (int ks = 0; ks < 2; ks++) {
      int slot = (((ks * 4 + q) ^ (rr & 7)) * 8);
      s16x8 aq0 = *(const s16x8*)&Qs[wm + rr][slot];
      s16x8 aq1 = *(const s16x8*)&Qs[wm + 16 + rr][slot];
      for (int j = 0; j < 4; j++) {
        s16x8 bk = *(const s16x8*)&Ks[j * 16 + rr][slot];
        S[0][j] = __builtin_amdgcn_mfma_f32_16x16x32_bf16(aq0, bk, S[0][j], 0, 0, 0);
        S[1][j] = __builtin_amdgcn_mfma_f32_16x16x32_bf16(aq1, bk, S[1][j], 0, 0, 0);
      }
    }

    // online softmax
    for (int i = 0; i < 2; i++) {
      for (int r = 0; r < 4; r++) {
        float mx = -1e30f;
        for (int j = 0; j < 4; j++) mx = fmaxf(mx, S[i][j][r]);
        for (int o = 1; o < 16; o <<= 1) mx = fmaxf(mx, __shfl_xor(mx, o));
        mx *= 0.125f;
        float mnew = fmaxf(mi[i][r], mx);
        float al = __expf(mi[i][r] - mnew);
        mi[i][r] = mnew;
        float ps = 0.f;
        for (int j = 0; j < 4; j++) {
          float e = __expf(S[i][j][r] * 0.125f - mnew);
          S[i][j][r] = e;
          ps += e;
        }
        for (int o = 1; o < 16; o <<= 1) ps += __shfl_xor(ps, o);
        li[i][r] = li[i][r] * al + ps;
        for (int jn = 0; jn < 4; jn++) O[i][jn][r] *= al;
      }
    }

    // P -> LDS (C-layout scatter)
    for (int i = 0; i < 2; i++)
      for (int j = 0; j < 4; j++)
        for (int r = 0; r < 4; r++)
          Ps[wm + i * 16 + q * 4 + r][j * 16 + rr] = f2bf(S[i][j][r]);
    __syncthreads();

    // O += P @ V
    for (int ks = 0; ks < 2; ks++) {
      s16x8 ap0 = *(const s16x8*)&Ps[wm + rr][ks * 32 + q * 8];
      s16x8 ap1 = *(const s16x8*)&Ps[wm + 16 + rr][ks * 32 + q * 8];
      int slot = (((ks * 4 + q) ^ (rr & 7)) * 8);
      for (int jn = 0; jn < 4; jn++) {
        s16x8 bv = *(const s16x8*)&Vs[jn * 16 + rr][slot];
        O[0][jn] = __builtin_amdgcn_mfma_f32_16x16x32_bf16(ap0, bv, O[0][jn], 0, 0, 0);
        O[1][jn] = __builtin_amdgcn_mfma_f32_16x16x32_bf16(ap1, bv, O[1][jn], 0, 0, 0);
      }
    }
  }

  // ---- epilogue: restage O through LDS (reuse Ps), full-line stores ----
  __syncthreads();                      // all PV ds_reads of Ps done
  u16* Pf = &Ps[0][0];                  // flat [128][64]
  for (int i = 0; i < 2; i++)
    for (int r = 0; r < 4; r++) {
      float inv = 1.f / li[i][r];
      int row = wm + i * 16 + q * 4 + r;
      for (int jn = 0; jn < 4; jn++)
        Pf[row * 64 + jn * 16 + rr] = f2bf(O[i][jn][r] * inv);
    }
  __syncthreads();
  for (int p = 0; p < 4; p++) {
    int row = p * 32 + (tid >> 3);
    int co  = (tid & 7) * 8;
    u16x8 vv = *(const u16x8*)&Pf[row * 64 + co];
    int s = qt * 128 + row;
    *(u16x8*)&o2[((long)(b * SLEN + s)) * DMODEL + h * 64 + co] = vv;
  }
}

// ---------------------------------------------------------------------------
// residual add (+out-proj bias, 2 split-K partials) + LayerNorm -> fp32+bf16
// ---------------------------------------------------------------------------
__global__ __launch_bounds__(256) void add_ln(const float* __restrict__ a,
                                              const float* __restrict__ p0,
                                              const float* __restrict__ p1,
                                              const float* __restrict__ ob,
                                              const float* __restrict__ g,
                                              const float* __restrict__ bb,
                                              float* __restrict__ xf, u16* __restrict__ xb) {
  int t = blockIdx.x, tid = threadIdx.x;
  float4 va = ((const float4*)(a + (long)t * DMODEL))[tid];
  float4 v0v = ((const float4*)(p0 + (long)t * DMODEL))[tid];
  float4 v1v = ((const float4*)(p1 + (long)t * DMODEL))[tid];
  float4 vo = ((const float4*)ob)[tid];
  float v0 = va.x + v0v.x + v1v.x + vo.x;
  float v1 = va.y + v0v.y + v1v.y + vo.y;
  float v2 = va.z + v0v.z + v1v.z + vo.z;
  float v3 = va.w + v0v.w + v1v.w + vo.w;
  float s = v0 + v1 + v2 + v3;
  float s2 = v0 * v0 + v1 * v1 + v2 * v2 + v3 * v3;
  __shared__ float sa[4], sb[4];
  for (int o = 32; o; o >>= 1) { s += __shfl_down(s, o); s2 += __shfl_down(s2, o); }
  int lane = tid & 63, w = tid >> 6;
  if (lane == 0) { sa[w] = s; sb[w] = s2; }
  __syncthreads();
  s = sa[0] + sa[1] + sa[2] + sa[3];
  s2 = sb[0] + sb[1] + sb[2] + sb[3];
  float mu = s * (1.f / DMODEL);
  float var = s2 * (1.f / DMODEL) - mu * mu;
  float rs = rsqrtf(var + LN_EPS);
  float4 gg = ((const float4*)g)[tid];
  float4 bv = ((const float4*)bb)[tid];
  float4 o;
  o.x = (v0 - mu) * rs * gg.x + bv.x;
  o.y = (v1 - mu) * rs * gg.y + bv.y;
  o.z = (v2 - mu) * rs * gg.z + bv.z;
  o.w = (v3 - mu) * rs * gg.w + bv.w;
  ((float4*)(xf + (long)t * DMODEL))[tid] = o;
  u16x4 obv;
  obv[0] = f2bf(o.x); obv[1] = f2bf(o.y); obv[2] = f2bf(o.z); obv[3] = f2bf(o.w);
  ((u16x4*)(xb + (long)t * DMODEL))[tid] = obv;
}

// ---------------------------------------------------------------------------
// Gate: logits, full softmax (usage/aux), top-2 routing lists
// ---------------------------------------------------------------------------
__global__ __launch_bounds__(256) void gate_kernel(
    const float* __restrict__ xf, const float* __restrict__ gw, const float* __restrict__ gb,
    int* __restrict__ cnt, int* __restrict__ tok_list,
    int* __restrict__ tk_e, int* __restrict__ tk_pos, float* __restrict__ tk_prob,
    float* __restrict__ usage) {
  int wid = threadIdx.x >> 6, lane = threadIdx.x & 63;
  int t = blockIdx.x * 4 + wid;
  float xv[16];
  for (int j = 0; j < 16; j++) xv[j] = xf[(long)t * DMODEL + j * 64 + lane];
  float l[8];
  for (int e = 0; e < 8; e++) {
    float d = 0.f;
    for (int j = 0; j < 16; j++) d += xv[j] * gw[e * DMODEL + j * 64 + lane];
    for (int o = 32; o; o >>= 1) d += __shfl_down(d, o);
    l[e] = d;  // valid on lane 0 only
  }
  __shared__ float us[8];
  if (threadIdx.x < 8) us[threadIdx.x] = 0.f;
  __syncthreads();
  if (lane == 0) {
    float mx = -1e30f;
    for (int e = 0; e < 8; e++) { l[e] += gb[e]; mx = fmaxf(mx, l[e]); }
    float ex[8], sum = 0.f;
    for (int e = 0; e < 8; e++) { ex[e] = expf(l[e] - mx); sum += ex[e]; }
    float inv = 1.f / sum;
    for (int e = 0; e < 8; e++) atomicAdd(&us[e], ex[e] * inv);
    int i1 = 0;
    for (int e = 1; e < 8; e++) if (l[e] > l[i1]) i1 = e;
    int i2 = (i1 == 0) ? 1 : 0;
    for (int e = 0; e < 8; e++) if (e != i1 && l[e] > l[i2]) i2 = e;
    float bb = expf(l[i2] - l[i1]);
    float p1 = 1.f / (1.f + bb), p2 = bb / (1.f + bb);
    int pos1 = atomicAdd(&cnt[i1], 1);
    tok_list[i1 * 2048 + pos1] = t;
    tk_e[2 * t] = i1; tk_pos[2 * t] = pos1; tk_prob[2 * t] = p1;
    int pos2 = atomicAdd(&cnt[i2], 1);
    tok_list[i2 * 2048 + pos2] = t;
    tk_e[2 * t + 1] = i2; tk_pos[2 * t + 1] = pos2; tk_prob[2 * t + 1] = p2;
  }
  __syncthreads();
  if (threadIdx.x < 8) atomicAdd(&usage[threadIdx.x], us[threadIdx.x]);
}

__global__ void finalize_gate(const int* __restrict__ cnt, int* __restrict__ offp,
                              const float* __restrict__ usage, float* __restrict__ aux_out) {
  if (threadIdx.x == 0) {
    int o = 0;
    for (int e = 0; e < 8; e++) { offp[e] = o; o += cnt[e]; }
    float s = 0.f;
    for (int e = 0; e < 8; e++) { float u = usage[e] * (1.f / T_TOK); s += u * u; }
    aux_out[0] = (float)NEXP * s;
  }
}

// gather x rows per expert into compact buffer
__global__ __launch_bounds__(256) void gather_x(const u16* __restrict__ xb,
                                                const int* __restrict__ cnt,
                                                const int* __restrict__ offp,
                                                const int* __restrict__ tok_list,
                                                u16* __restrict__ xg) {
  int e = blockIdx.y, i = blockIdx.x;
  if (i >= cnt[e]) return;
  int t = tok_list[e * 2048 + i];
  long j = offp[e] + i;
  ((uint2*)(xg + j * DMODEL))[threadIdx.x] =
      ((const uint2*)(xb + (long)t * DMODEL))[threadIdx.x];
}

// weighted expert-output combine + residual + LN2 -> final output
__global__ __launch_bounds__(256) void moe_ln2(
    const float* __restrict__ xf, const float* __restrict__ y,
    const int* __restrict__ offp, const int* __restrict__ tk_e,
    const int* __restrict__ tk_pos, const float* __restrict__ tk_prob,
    const float* __restrict__ g, const float* __restrict__ bb, float* __restrict__ out) {
  int t = blockIdx.x, tid = threadIdx.x;
  int e0 = tk_e[2 * t], e1 = tk_e[2 * t + 1];
  long j0 = (long)offp[e0] + tk_pos[2 * t];
  long j1 = (long)offp[e1] + tk_pos[2 * t + 1];
  float p0 = tk_prob[2 * t], p1 = tk_prob[2 * t + 1];
  float4 vx = ((const float4*)(xf + (long)t * DMODEL))[tid];
  float4 y0 = ((const float4*)(y + j0 * DMODEL))[tid];
  float4 y1 = ((const float4*)(y + j1 * DMODEL))[tid];
  float v0 = vx.x + p0 * y0.x + p1 * y1.x;
  float v1 = vx.y + p0 * y0.y + p1 * y1.y;
  float v2 = vx.z + p0 * y0.z + p1 * y1.z;
  float v3 = vx.w + p0 * y0.w + p1 * y1.w;
  float s = v0 + v1 + v2 + v3;
  float s2 = v0 * v0 + v1 * v1 + v2 * v2 + v3 * v3;
  __shared__ float sa[4], sb[4];
  for (int o = 32; o; o >>= 1) { s += __shfl_down(s, o); s2 += __shfl_down(s2, o); }
  int lane = tid & 63, w = tid >> 6;
  if (lane == 0) { sa[w] = s; sb[w] = s2; }
  __syncthreads();
  s = sa[0] + sa[1] + sa[2] + sa[3];
  s2 = sb[0] + sb[1] + sb[2] + sb[3];
  float mu = s * (1.f / DMODEL);
  float var = s2 * (1.f / DMODEL) - mu * mu;
  float rs = rsqrtf(var + LN_EPS);
  float4 gg = ((const float4*)g)[tid];
  float4 bv = ((const float4*)bb)[tid];
  float4 o;
  o.x = (v0 - mu) * rs * gg.x + bv.x;
  o.y = (v1 - mu) * rs * gg.y + bv.y;
  o.z = (v2 - mu) * rs * gg.z + bv.z;
  o.w = (v3 - mu) * rs * gg.w + bv.w;
  ((float4*)(out + (long)t * DMODEL))[tid] = o;
}

// ---------------------------------------------------------------------------
extern "C" void kernel_launch(void* const* d_in, const int* in_sizes, int n_in,
                              void* d_out, int out_size, void* d_ws, size_t ws_size,
                              hipStream_t stream) {
  const float* src  = (const float*)d_in[0];
  const float* inw  = (const float*)d_in[1];
  const float* inb  = (const float*)d_in[2];
  const float* outw = (const float*)d_in[3];
  const float* outb = (const float*)d_in[4];
  const float* gw   = (const float*)d_in[5];
  const float* gb   = (const float*)d_in[6];
  const float* w1   = (const float*)d_in[7];
  const float* b1   = (const float*)d_in[8];
  const float* w2   = (const float*)d_in[9];
  const float* b2   = (const float*)d_in[10];
  const float* g1   = (const float*)d_in[11];
  const float* bb1  = (const float*)d_in[12];
  const float* g2   = (const float*)d_in[13];
  const float* bb2  = (const float*)d_in[14];
  float* out = (float*)d_out;

  char* w = (char*)d_ws;
  auto alloc = [&](size_t bytes) {
    char* p = w;
    w += (bytes + 255) & ~(size_t)255;
    return p;
  };

  int*   cnt     = (int*)alloc(8 * 4);
  int*   offp    = (int*)alloc(8 * 4);
  float* usage   = (float*)alloc(8 * 4);
  int*   tok_list= (int*)alloc((size_t)NEXP * 2048 * 4);
  int*   tk_e    = (int*)alloc((size_t)2 * T_TOK * 4);
  int*   tk_pos  = (int*)alloc((size_t)2 * T_TOK * 4);
  float* tk_prob = (float*)alloc((size_t)2 * T_TOK * 4);

  u16* src_bf  = (u16*)alloc((size_t)T_TOK * DMODEL * 2);
  u16* inw_bf  = (u16*)alloc((size_t)3 * DMODEL * DMODEL * 2);
  u16* outw_bf = (u16*)alloc((size_t)DMODEL * DMODEL * 2);
  u16* w1_bf   = (u16*)alloc((size_t)NEXP * FDIM * DMODEL * 2);
  u16* w2_bf   = (u16*)alloc((size_t)NEXP * DMODEL * FDIM * 2);
  u16* qkv_bf  = (u16*)alloc((size_t)T_TOK * 3 * DMODEL * 2);
  u16* vt_bf   = (u16*)alloc((size_t)T_TOK * DMODEL * 2);    // (B,H,HD,S)
  u16* o2_bf   = (u16*)alloc((size_t)T_TOK * DMODEL * 2);    // (B,S,D)
  float* attn_p= (float*)alloc((size_t)2 * T_TOK * DMODEL * 4);  // 2 split-K partials
  float* x_f   = (float*)alloc((size_t)T_TOK * DMODEL * 4);
  u16* x_bf    = (u16*)alloc((size_t)T_TOK * DMODEL * 2);
  u16* xg_bf   = (u16*)alloc((size_t)2 * T_TOK * DMODEL * 2);
  u16* h_bf    = (u16*)alloc((size_t)2 * T_TOK * FDIM * 2);
  float* y_f   = (float*)alloc((size_t)2 * T_TOK * DMODEL * 4);
  (void)ws_size; (void)n_in; (void)in_sizes; (void)out_size;

  hipMemsetAsync(cnt, 0, 3 * 256, stream);  // cnt, offp, usage regions

  // bf16 conversions
  cvt_small<<<(T_TOK * DMODEL / 4 + 255) / 256, 256, 0, stream>>>(src, src_bf, T_TOK * DMODEL / 4);
  cvt_small<<<(3 * DMODEL * DMODEL / 4 + 255) / 256, 256, 0, stream>>>(inw, inw_bf, 3L * DMODEL * DMODEL / 4);
  cvt_small<<<(DMODEL * DMODEL / 4 + 255) / 256, 256, 0, stream>>>(outw, outw_bf, (long)DMODEL * DMODEL / 4);
  cvt_w1<<<(int)((long)NEXP * FDIM * DMODEL / 4 / 256), 256, 0, stream>>>(w1, w1_bf, (long)NEXP * FDIM * DMODEL / 4);
  cvt_w2<<<(int)((long)NEXP * DMODEL * FDIM / 4 / 256), 256, 0, stream>>>(w2, w2_bf, (long)NEXP * DMODEL * FDIM / 4);

  // QKV projection: (2048x1024) @ (3072x1024)^T + b -> bf16
  k_qkv<<<dim3(24, 32), 256, 0, stream>>>(src_bf, inw_bf, qkv_bf, inb);

  transpose_v<<<dim3(16, 32), 256, 0, stream>>>(qkv_bf, vt_bf);

  // fused flash attention -> o2_bf (B,S,D)
  fused_attn<<<dim3(8, 32), 256, 0, stream>>>(qkv_bf, vt_bf, o2_bf);

  // output projection, split-K=2 -> two fp32 partials (bias folded into add_ln)
  k_outp<<<dim3(8, 32, 2), 256, 0, stream>>>(o2_bf, outw_bf, attn_p);

  // residual + out-proj bias + LN1
  add_ln<<<T_TOK, 256, 0, stream>>>(src, attn_p, attn_p + (long)T_TOK * DMODEL,
                                    outb, g1, bb1, x_f, x_bf);

  // gate + routing
  gate_kernel<<<T_TOK / 4, 256, 0, stream>>>(x_f, gw, gb, cnt, tok_list,
                                             tk_e, tk_pos, tk_prob, usage);
  finalize_gate<<<1, 64, 0, stream>>>(cnt, offp, usage, out + (long)T_TOK * DMODEL);

  gather_x<<<dim3(2048, 8), 256, 0, stream>>>(x_bf, cnt, offp, tok_list, xg_bf);

  // FFN1 (grouped, gelu fused) -> bf16
  k_ffn1<<<dim3(32, 16, 8), 256, 0, stream>>>(xg_bf, w1_bf, h_bf, b1, cnt, offp);

  // FFN2 (grouped) -> fp32
  k_ffn2<<<dim3(8, 32, 8), 256, 0, stream>>>(h_bf, w2_bf, y_f, b2, cnt, offp);

  // combine + residual + LN2 -> output
  moe_ln2<<<T_TOK, 256, 0, stream>>>(x_f, y_f, offp, tk_e, tk_pos, tk_prob,
                                     g2, bb2, out);
}

// Round 5
// 645.792 us; speedup vs baseline: 1.2427x; 1.0406x over previous
//
#include <hip/hip_runtime.h>
#include <stdint.h>
#include <stddef.h>

// Problem constants
#define T_TOK 2048     // B*S tokens
#define DMODEL 1024
#define NHEAD 16
#define HDIM 64
#define NEXP 8
#define FDIM 4096
#define SLEN 1024
#define NBATCH 2
#define LN_EPS 1e-5f

typedef unsigned short u16;
typedef __attribute__((ext_vector_type(8))) short s16x8;   // 8 bf16 MFMA frag
typedef __attribute__((ext_vector_type(4))) float f32x4;   // MFMA accumulator
typedef __attribute__((ext_vector_type(4))) unsigned short u16x4;
typedef __attribute__((ext_vector_type(8))) unsigned short u16x8;

typedef __attribute__((address_space(1))) void gvoid;      // global
typedef __attribute__((address_space(3))) void lvoid;      // LDS

__device__ __forceinline__ u16 f2bf(float x) {
  union { float f; unsigned int u; } v; v.f = x;
  unsigned int r = v.u + 0x7fffu + ((v.u >> 16) & 1u);  // RNE
  return (u16)(r >> 16);
}

// async global->LDS, 16B/lane. Dest is wave-uniform base; HW adds lane*16.
__device__ __forceinline__ void gl_lds16(const u16* g, u16* lds_base) {
  __builtin_amdgcn_global_load_lds((gvoid*)g, (lvoid*)lds_base, 16, 0, 0);
}

// ---------------------------------------------------------------------------
// fp32 -> bf16 convert (named clones for profile attribution)
// ---------------------------------------------------------------------------
__device__ __forceinline__ void cvt_body(const float* __restrict__ x,
                                         u16* __restrict__ y, long n4) {
  long i = (long)blockIdx.x * 256 + threadIdx.x;
  if (i >= n4) return;
  float4 v = ((const float4*)x)[i];
  u16x4 o;
  o[0] = f2bf(v.x); o[1] = f2bf(v.y); o[2] = f2bf(v.z); o[3] = f2bf(v.w);
  ((u16x4*)y)[i] = o;
}
__global__ __launch_bounds__(256) void cvt_small(const float* x, u16* y, long n4) { cvt_body(x, y, n4); }
__global__ __launch_bounds__(256) void cvt_w1(const float* x, u16* y, long n4) { cvt_body(x, y, n4); }
__global__ __launch_bounds__(256) void cvt_w2(const float* x, u16* y, long n4) { cvt_body(x, y, n4); }

// ---------------------------------------------------------------------------
// Pipelined GEMM body: C = act(A @ B^T + bias), BN=128, BM in {64,128}.
// Double-buffered LDS, prefetch distance 2, raw s_barrier + partial vmcnt
// waits (never vmcnt(0) mid-loop) so tile k+1's DMA stays in flight while
// tile k is computed.
// Epilogue: restage output tile through LDS (reusing the dead As/Bs buffers)
// so every global store instruction covers full 128B lines.
// ---------------------------------------------------------------------------
template<int BM, int OUTBF, int DOGELU>
__device__ __forceinline__ void gemm_body(
    const u16* __restrict__ A, long lda,
    const u16* __restrict__ Bp, long ldb,
    char* __restrict__ C, long ldc,
    const float* __restrict__ bias,
    int Mloc, int k0start, int Kc, int m0, int n0) {
  constexpr int AS_BYTES = 2 * BM * 64 * 2;
  constexpr int SMEM_BYTES = AS_BYTES + 2 * 128 * 64 * 2;   // As + Bs
  __shared__ __align__(16) char smem[SMEM_BYTES];
  u16 (*As)[BM][64]  = reinterpret_cast<u16(*)[BM][64]>(smem);
  u16 (*Bs)[128][64] = reinterpret_cast<u16(*)[128][64]>(smem + AS_BYTES);

  constexpr int SM = BM / 32;           // M-frags per wave
  constexpr int LPI = BM / 32 + 4;      // gl_lds insts per wave per tile

  int tid = threadIdx.x;
  int lane = tid & 63, w = tid >> 6;
  int lrow = lane >> 3;                 // 0..7
  int sg8 = ((lane & 7) ^ lrow) * 8;    // XOR-swizzled source granule
  int q = lane >> 4, rr = lane & 15;
  int wm = (w & 1) * (BM / 2), wn = (w >> 1) * 64;
  int NIT = Kc >> 6;

  auto issue = [&](int kt, int b) {
    int k0 = k0start + (kt << 6);
    for (int p = 0; p < BM / 32; p++) {
      int rb = p * 32 + w * 8;
      int gr = m0 + rb + lrow; if (gr > Mloc - 1) gr = Mloc - 1;   // M-tail clamp
      gl_lds16(A + (long)gr * lda + k0 + sg8, &As[b][rb][0]);
    }
    for (int p = 0; p < 4; p++) {
      int rb = p * 32 + w * 8;
      gl_lds16(Bp + (long)(n0 + rb + lrow) * ldb + k0 + sg8, &Bs[b][rb][0]);
    }
  };

  f32x4 acc[SM][4];
  for (int i = 0; i < SM; i++)
    for (int j = 0; j < 4; j++)
      for (int r = 0; r < 4; r++) acc[i][j][r] = 0.f;

  issue(0, 0);
  if (NIT > 1) issue(1, 1);

  int slot0 = ((q ^ (rr & 7)) * 8);           // kk=0 swizzled slot
  int slot1 = (((4 + q) ^ (rr & 7)) * 8);     // kk=1

  for (int kt = 0; kt < NIT; kt++) {
    int b = kt & 1;
    // wait for tile kt only; tile kt+1's LPI loads remain outstanding
    if (kt + 1 < NIT)
      asm volatile("s_waitcnt vmcnt(%0)" :: "i"(LPI) : "memory");
    else
      asm volatile("s_waitcnt vmcnt(0)" ::: "memory");
    asm volatile("s_barrier" ::: "memory");

    s16x8 a0[SM], a1[SM], b0[4], b1[4];
    for (int i = 0; i < SM; i++) {
      a0[i] = *(const s16x8*)&As[b][wm + i * 16 + rr][slot0];
      a1[i] = *(const s16x8*)&As[b][wm + i * 16 + rr][slot1];
    }
    for (int j = 0; j < 4; j++) {
      b0[j] = *(const s16x8*)&Bs[b][wn + j * 16 + rr][slot0];
      b1[j] = *(const s16x8*)&Bs[b][wn + j * 16 + rr][slot1];
    }
    asm volatile("s_waitcnt lgkmcnt(0)" ::: "memory");  // frags in regs
    asm volatile("s_barrier" ::: "memory");             // all waves done reading buf b
    if (kt + 2 < NIT) issue(kt + 2, b);                 // overwrite buf b (visible at kt+2)

    for (int i = 0; i < SM; i++)
      for (int j = 0; j < 4; j++) {
        acc[i][j] = __builtin_amdgcn_mfma_f32_16x16x32_bf16(a0[i], b0[j], acc[i][j], 0, 0, 0);
        acc[i][j] = __builtin_amdgcn_mfma_f32_16x16x32_bf16(a1[i], b1[j], acc[i][j], 0, 0, 0);
      }
  }

  // ---- epilogue: stage through LDS, then full-line coalesced stores ----
  u16*   Cu = (u16*)smem;     // [BM][128] bf16 tile
  float* Cf = (float*)smem;   // [BM][128] fp32 tile
  for (int i = 0; i < SM; i++)
    for (int j = 0; j < 4; j++) {
      int col = wn + j * 16 + rr;
      float bv = bias ? bias[n0 + col] : 0.f;
      for (int r = 0; r < 4; r++) {
        int row = wm + i * 16 + q * 4 + r;
        float v = acc[i][j][r] + bv;
        if (DOGELU) v = 0.5f * v * (1.f + erff(v * 0.70710678118f));
        if (OUTBF) Cu[row * 128 + col] = f2bf(v);
        else       Cf[row * 128 + col] = v;
      }
    }
  __syncthreads();
  if (OUTBF) {
    for (int p = 0; p < BM / 16; p++) {
      int row = p * 16 + (tid >> 4);
      int co  = (tid & 15) * 8;
      if (m0 + row < Mloc) {
        u16x8 vv = *(const u16x8*)&Cu[row * 128 + co];
        *(u16x8*)((u16*)C + (long)(m0 + row) * ldc + n0 + co) = vv;
      }
    }
  } else {
    for (int p = 0; p < BM / 8; p++) {
      int row = p * 8 + (tid >> 5);
      int co  = (tid & 31) * 4;
      if (m0 + row < Mloc) {
        float4 vv = *(const float4*)&Cf[row * 128 + co];
        *(float4*)((float*)C + (long)(m0 + row) * ldc + n0 + co) = vv;
      }
    }
  }
}

// ---- named GEMM wrappers (R0 grids: balanced round-robin across XCDs) -----
__global__ __launch_bounds__(256) void k_qkv(const u16* __restrict__ A,
                                             const u16* __restrict__ B,
                                             u16* __restrict__ C,
                                             const float* __restrict__ bias) {
  gemm_body<64, 1, 0>(A, DMODEL, B, DMODEL, (char*)C, 3 * DMODEL, bias,
                      T_TOK, 0, DMODEL, blockIdx.y * 64, blockIdx.x * 128);
}

// out-projection, split-K=2: z picks K-half, writes partial buffer z
__global__ __launch_bounds__(256) void k_outp(const u16* __restrict__ A,
                                              const u16* __restrict__ B,
                                              float* __restrict__ Cpart) {
  int z = blockIdx.z;
  char* C = (char*)(Cpart + (long)z * T_TOK * DMODEL);
  gemm_body<64, 0, 0>(A, DMODEL, B, DMODEL, C, DMODEL, nullptr,
                      T_TOK, z * 512, 512, blockIdx.y * 64, blockIdx.x * 128);
}

__global__ __launch_bounds__(256) void k_ffn1(const u16* __restrict__ Ag,
                                              const u16* __restrict__ Bg,
                                              u16* __restrict__ Cg,
                                              const float* __restrict__ biasg,
                                              const int* __restrict__ cntp,
                                              const int* __restrict__ offp) {
  int z = blockIdx.z;
  int Mloc = cntp[z];
  int m0 = blockIdx.y * 128;
  if (m0 >= Mloc) return;
  long o = offp[z];
  gemm_body<128, 1, 1>(Ag + o * DMODEL, DMODEL,
                       Bg + (long)z * FDIM * DMODEL, DMODEL,
                       (char*)(Cg + o * FDIM), FDIM,
                       biasg + (long)z * FDIM,
                       Mloc, 0, DMODEL, m0, blockIdx.x * 128);
}

// FFN2: BM=128 (2x MFMA per barrier vs BM=64) + split-K=2 (keeps ~512 active
// blocks = 2/CU). Bias + partial combine moved to moe_ln2.
__global__ __launch_bounds__(256) void k_ffn2(const u16* __restrict__ Ag,
                                              const u16* __restrict__ Bg,
                                              float* __restrict__ Cpart,
                                              const int* __restrict__ cntp,
                                              const int* __restrict__ offp) {
  int zz = blockIdx.z;                 // 0..15 = kh*8 + expert
  int z = zz & 7, kh = zz >> 3;
  int Mloc = cntp[z];
  int m0 = blockIdx.y * 128;
  if (m0 >= Mloc) return;
  long o = offp[z];
  float* C = Cpart + (long)kh * 2 * T_TOK * DMODEL;
  gemm_body<128, 0, 0>(Ag + o * FDIM, FDIM,
                       Bg + (long)z * DMODEL * FDIM, FDIM,
                       (char*)(C + o * DMODEL), DMODEL,
                       nullptr,
                       Mloc, kh * 2048, 2048, m0, blockIdx.x * 128);
}

// ---------------------------------------------------------------------------
// V part of qkv -> Vt (B,H,HD,S) bf16 (transposed via LDS tile)
// ---------------------------------------------------------------------------
__global__ __launch_bounds__(256) void transpose_v(const u16* __restrict__ qkv,
                                                   u16* __restrict__ vt) {
  __shared__ u16 tile[64][65];
  int s0 = blockIdx.x * 64, bh = blockIdx.y;
  int b = bh >> 4, h = bh & 15;
  int r = threadIdx.x >> 3, c = (threadIdx.x & 7) * 8;
  for (int p = 0; p < 64; p += 32) {
    u16x8 v = *(const u16x8*)&qkv[(long)(b * SLEN + s0 + p + r) * 3072 + 2048 + h * 64 + c];
    for (int j = 0; j < 8; j++) tile[p + r][c + j] = v[j];
  }
  __syncthreads();
  for (int p = 0; p < 64; p += 32) {
    int d = p + r;
    u16x8 v;
    for (int j = 0; j < 8; j++) v[j] = tile[c + j][d];
    *(u16x8*)&vt[((long)bh * 64 + d) * SLEN + s0 + c] = v;
  }
}

// ---------------------------------------------------------------------------
// Fused flash attention: per (q-tile 128, b*h) block. Writes (B,S,D) bf16.
// K/V double-buffered with DMA prefetch; ONE barrier per K-tile:
//  - top: vmcnt(0) (own DMA done) + s_barrier (all waves' DMA done, prev
//    iteration's LDS reads complete) -> safe to read buf and overwrite !buf.
//  - P-scatter -> PV needs no barrier: each wave's Ps band (rows wm..wm+31)
//    is written AND read only by that wave; in-wave ds ordering (lgkmcnt,
//    compiler-inserted) suffices.
// ---------------------------------------------------------------------------
__global__ __launch_bounds__(256) void fused_attn(const u16* __restrict__ qkv,
                                                  const u16* __restrict__ vt,
                                                  u16* __restrict__ o2) {
  __shared__ u16 Qs[128][64];      // swizzled
  __shared__ u16 Ks[2][64][64];    // swizzled, double-buffered
  __shared__ u16 Vs[2][64][64];    // swizzled (rows = head-dim d, cols = keys)
  __shared__ u16 Ps[128][72];      // padded

  int qt = blockIdx.x, bh = blockIdx.y;
  int b = bh >> 4, h = bh & 15;
  const u16* base = qkv + (long)b * SLEN * 3072 + h * 64;
  const u16* vbase = vt + (long)bh * HDIM * SLEN;

  int tid = threadIdx.x, lane = tid & 63, w = tid >> 6;
  int lrow = lane >> 3;
  int sg8 = ((lane & 7) ^ lrow) * 8;
  int q = lane >> 4, rr = lane & 15;
  int wm = w * 32;

  auto issue_kv = [&](int kt, int bf) {
    for (int p = 0; p < 2; p++) {
      int rb = p * 32 + w * 8;
      gl_lds16(base + (long)(kt * 64 + rb + lrow) * 3072 + 1024 + sg8, &Ks[bf][rb][0]);
      gl_lds16(vbase + (long)(rb + lrow) * SLEN + kt * 64 + sg8, &Vs[bf][rb][0]);
    }
  };

  // stage Q once + first K/V tile
  for (int p = 0; p < 4; p++) {
    int rb = p * 32 + w * 8;
    gl_lds16(base + (long)(qt * 128 + rb + lrow) * 3072 + sg8, &Qs[rb][0]);
  }
  issue_kv(0, 0);

  f32x4 O[2][4];
  float mi[2][4], li[2][4];
  for (int i = 0; i < 2; i++)
    for (int r = 0; r < 4; r++) { mi[i][r] = -1e30f; li[i][r] = 0.f; }
  for (int i = 0; i < 2; i++)
    for (int jn = 0; jn < 4; jn++)
      for (int r = 0; r < 4; r++) O[i][jn][r] = 0.f;

  for (int kt = 0; kt < 16; kt++) {
    int bf = kt & 1;
    asm volatile("s_waitcnt vmcnt(0)" ::: "memory");   // own DMA for tile kt landed
    asm volatile("s_barrier" ::: "memory");            // all waves' DMA landed; prev iter done
    if (kt + 1 < 16) issue_kv(kt + 1, bf ^ 1);         // prefetch overlaps full iteration

    // S = Q @ K^T
    f32x4 S[2][4];
    for (int i = 0; i < 2; i++)
      for (int j = 0; j < 4; j++)
        for (int r = 0; r < 4; r++) S[i][j][r] = 0.f;
    for (int ks = 0; ks < 2; ks++) {
      int slot = (((ks * 4 + q) ^ (rr & 7)) * 8);
      s16x8 aq0 = *(const s16x8*)&Qs[wm + rr][slot];
      s16x8 aq1 = *(const s16x8*)&Qs[wm + 16 + rr][slot];
      for (int j = 0; j < 4; j++) {
        s16x8 bk = *(const s16x8*)&Ks[bf][j * 16 + rr][slot];
        S[0][j] = __builtin_amdgcn_mfma_f32_16x16x32_bf16(aq0, bk, S[0][j], 0, 0, 0);
        S[1][j] = __builtin_amdgcn_mfma_f32_16x16x32_bf16(aq1, bk, S[1][j], 0, 0, 0);
      }
    }

    // online softmax
    for (int i = 0; i < 2; i++) {
      for (int r = 0; r < 4; r++) {
        float mx = -1e30f;
        for (int j = 0; j < 4; j++) mx = fmaxf(mx, S[i][j][r]);
        for (int o = 1; o < 16; o <<= 1) mx = fmaxf(mx, __shfl_xor(mx, o));
        mx *= 0.125f;
        float mnew = fmaxf(mi[i][r], mx);
        float al = __expf(mi[i][r] - mnew);
        mi[i][r] = mnew;
        float ps = 0.f;
        for (int j = 0; j < 4; j++) {
          float e = __expf(S[i][j][r] * 0.125f - mnew);
          S[i][j][r] = e;
          ps += e;
        }
        for (int o = 1; o < 16; o <<= 1) ps += __shfl_xor(ps, o);
        li[i][r] = li[i][r] * al + ps;
        for (int jn = 0; jn < 4; jn++) O[i][jn][r] *= al;
      }
    }

    // P -> LDS (wave-private band: rows wm..wm+31)
    for (int i = 0; i < 2; i++)
      for (int j = 0; j < 4; j++)
        for (int r = 0; r < 4; r++)
          Ps[wm + i * 16 + q * 4 + r][j * 16 + rr] = f2bf(S[i][j][r]);

    // O += P @ V  (Ps reads are same-wave band; compiler orders ds ops)
    for (int ks = 0; ks < 2; ks++) {
      s16x8 ap0 = *(const s16x8*)&Ps[wm + rr][ks * 32 + q * 8];
      s16x8 ap1 = *(const s16x8*)&Ps[wm + 16 + rr][ks * 32 + q * 8];
      int slot = (((ks * 4 + q) ^ (rr & 7)) * 8);
      for (int jn = 0; jn < 4; jn++) {
        s16x8 bv = *(const s16x8*)&Vs[bf][jn * 16 + rr][slot];
        O[0][jn] = __builtin_amdgcn_mfma_f32_16x16x32_bf16(ap0, bv, O[0][jn], 0, 0, 0);
        O[1][jn] = __builtin_amdgcn_mfma_f32_16x16x32_bf16(ap1, bv, O[1][jn], 0, 0, 0);
      }
    }
  }

  // ---- epilogue: restage O through LDS (reuse Ps), full-line stores ----
  __syncthreads();                      // all PV ds_reads of Ps done (cross-band alias)
  u16* Pf = &Ps[0][0];                  // flat [128][64]
  for (int i = 0; i < 2; i++)
    for (int r = 0; r < 4; r++) {
      float inv = 1.f / li[i][r];
      int row = wm + i * 16 + q * 4 + r;
      for (int jn = 0; jn < 4; jn++)
        Pf[row * 64 + jn * 16 + rr] = f2bf(O[i][jn][r] * inv);
    }
  __syncthreads();
  for (int p = 0; p < 4; p++) {
    int row = p * 32 + (tid >> 3);
    int co  = (tid & 7) * 8;
    u16x8 vv = *(const u16x8*)&Pf[row * 64 + co];
    int s = qt * 128 + row;
    *(u16x8*)&o2[((long)(b * SLEN + s)) * DMODEL + h * 64 + co] = vv;
  }
}

// ---------------------------------------------------------------------------
// residual add (+out-proj bias, 2 split-K partials) + LayerNorm -> fp32+bf16
// ---------------------------------------------------------------------------
__global__ __launch_bounds__(256) void add_ln(const float* __restrict__ a,
                                              const float* __restrict__ p0,
                                              const float* __restrict__ p1,
                                              const float* __restrict__ ob,
                                              const float* __restrict__ g,
                                              const float* __restrict__ bb,
                                              float* __restrict__ xf, u16* __restrict__ xb) {
  int t = blockIdx.x, tid = threadIdx.x;
  float4 va = ((const float4*)(a + (long)t * DMODEL))[tid];
  float4 v0v = ((const float4*)(p0 + (long)t * DMODEL))[tid];
  float4 v1v = ((const float4*)(p1 + (long)t * DMODEL))[tid];
  float4 vo = ((const float4*)ob)[tid];
  float v0 = va.x + v0v.x + v1v.x + vo.x;
  float v1 = va.y + v0v.y + v1v.y + vo.y;
  float v2 = va.z + v0v.z + v1v.z + vo.z;
  float v3 = va.w + v0v.w + v1v.w + vo.w;
  float s = v0 + v1 + v2 + v3;
  float s2 = v0 * v0 + v1 * v1 + v2 * v2 + v3 * v3;
  __shared__ float sa[4], sb[4];
  for (int o = 32; o; o >>= 1) { s += __shfl_down(s, o); s2 += __shfl_down(s2, o); }
  int lane = tid & 63, w = tid >> 6;
  if (lane == 0) { sa[w] = s; sb[w] = s2; }
  __syncthreads();
  s = sa[0] + sa[1] + sa[2] + sa[3];
  s2 = sb[0] + sb[1] + sb[2] + sb[3];
  float mu = s * (1.f / DMODEL);
  float var = s2 * (1.f / DMODEL) - mu * mu;
  float rs = rsqrtf(var + LN_EPS);
  float4 gg = ((const float4*)g)[tid];
  float4 bv = ((const float4*)bb)[tid];
  float4 o;
  o.x = (v0 - mu) * rs * gg.x + bv.x;
  o.y = (v1 - mu) * rs * gg.y + bv.y;
  o.z = (v2 - mu) * rs * gg.z + bv.z;
  o.w = (v3 - mu) * rs * gg.w + bv.w;
  ((float4*)(xf + (long)t * DMODEL))[tid] = o;
  u16x4 obv;
  obv[0] = f2bf(o.x); obv[1] = f2bf(o.y); obv[2] = f2bf(o.z); obv[3] = f2bf(o.w);
  ((u16x4*)(xb + (long)t * DMODEL))[tid] = obv;
}

// ---------------------------------------------------------------------------
// Gate: logits, full softmax (usage/aux), top-2 routing lists
// ---------------------------------------------------------------------------
__global__ __launch_bounds__(256) void gate_kernel(
    const float* __restrict__ xf, const float* __restrict__ gw, const float* __restrict__ gb,
    int* __restrict__ cnt, int* __restrict__ tok_list,
    int* __restrict__ tk_e, int* __restrict__ tk_pos, float* __restrict__ tk_prob,
    float* __restrict__ usage) {
  int wid = threadIdx.x >> 6, lane = threadIdx.x & 63;
  int t = blockIdx.x * 4 + wid;
  float xv[16];
  for (int j = 0; j < 16; j++) xv[j] = xf[(long)t * DMODEL + j * 64 + lane];
  float l[8];
  for (int e = 0; e < 8; e++) {
    float d = 0.f;
    for (int j = 0; j < 16; j++) d += xv[j] * gw[e * DMODEL + j * 64 + lane];
    for (int o = 32; o; o >>= 1) d += __shfl_down(d, o);
    l[e] = d;  // valid on lane 0 only
  }
  __shared__ float us[8];
  if (threadIdx.x < 8) us[threadIdx.x] = 0.f;
  __syncthreads();
  if (lane == 0) {
    float mx = -1e30f;
    for (int e = 0; e < 8; e++) { l[e] += gb[e]; mx = fmaxf(mx, l[e]); }
    float ex[8], sum = 0.f;
    for (int e = 0; e < 8; e++) { ex[e] = expf(l[e] - mx); sum += ex[e]; }
    float inv = 1.f / sum;
    for (int e = 0; e < 8; e++) atomicAdd(&us[e], ex[e] * inv);
    int i1 = 0;
    for (int e = 1; e < 8; e++) if (l[e] > l[i1]) i1 = e;
    int i2 = (i1 == 0) ? 1 : 0;
    for (int e = 0; e < 8; e++) if (e != i1 && l[e] > l[i2]) i2 = e;
    float bb = expf(l[i2] - l[i1]);
    float p1 = 1.f / (1.f + bb), p2 = bb / (1.f + bb);
    int pos1 = atomicAdd(&cnt[i1], 1);
    tok_list[i1 * 2048 + pos1] = t;
    tk_e[2 * t] = i1; tk_pos[2 * t] = pos1; tk_prob[2 * t] = p1;
    int pos2 = atomicAdd(&cnt[i2], 1);
    tok_list[i2 * 2048 + pos2] = t;
    tk_e[2 * t + 1] = i2; tk_pos[2 * t + 1] = pos2; tk_prob[2 * t + 1] = p2;
  }
  __syncthreads();
  if (threadIdx.x < 8) atomicAdd(&usage[threadIdx.x], us[threadIdx.x]);
}

__global__ void finalize_gate(const int* __restrict__ cnt, int* __restrict__ offp,
                              const float* __restrict__ usage, float* __restrict__ aux_out) {
  if (threadIdx.x == 0) {
    int o = 0;
    for (int e = 0; e < 8; e++) { offp[e] = o; o += cnt[e]; }
    float s = 0.f;
    for (int e = 0; e < 8; e++) { float u = usage[e] * (1.f / T_TOK); s += u * u; }
    aux_out[0] = (float)NEXP * s;
  }
}

// gather x rows per expert into compact buffer
__global__ __launch_bounds__(256) void gather_x(const u16* __restrict__ xb,
                                                const int* __restrict__ cnt,
                                                const int* __restrict__ offp,
                                                const int* __restrict__ tok_list,
                                                u16* __restrict__ xg) {
  int e = blockIdx.y, i = blockIdx.x;
  if (i >= cnt[e]) return;
  int t = tok_list[e * 2048 + i];
  long j = offp[e] + i;
  ((uint2*)(xg + j * DMODEL))[threadIdx.x] =
      ((const uint2*)(xb + (long)t * DMODEL))[threadIdx.x];
}

// weighted expert-output combine (2 split-K partials + b2 bias) + residual
// + LN2 -> final output
__global__ __launch_bounds__(256) void moe_ln2(
    const float* __restrict__ xf, const float* __restrict__ y,
    const float* __restrict__ b2g,
    const int* __restrict__ offp, const int* __restrict__ tk_e,
    const int* __restrict__ tk_pos, const float* __restrict__ tk_prob,
    const float* __restrict__ g, const float* __restrict__ bb, float* __restrict__ out) {
  const long HALF = (long)2 * T_TOK * DMODEL;
  int t = blockIdx.x, tid = threadIdx.x;
  int e0 = tk_e[2 * t], e1 = tk_e[2 * t + 1];
  long j0 = (long)offp[e0] + tk_pos[2 * t];
  long j1 = (long)offp[e1] + tk_pos[2 * t + 1];
  float p0 = tk_prob[2 * t], p1 = tk_prob[2 * t + 1];
  float4 vx = ((const float4*)(xf + (long)t * DMODEL))[tid];
  float4 y0a = ((const float4*)(y + j0 * DMODEL))[tid];
  float4 y0b = ((const float4*)(y + HALF + j0 * DMODEL))[tid];
  float4 y1a = ((const float4*)(y + j1 * DMODEL))[tid];
  float4 y1b = ((const float4*)(y + HALF + j1 * DMODEL))[tid];
  float4 b0v = ((const float4*)(b2g + (long)e0 * DMODEL))[tid];
  float4 b1v = ((const float4*)(b2g + (long)e1 * DMODEL))[tid];
  float v0 = vx.x + p0 * (y0a.x + y0b.x + b0v.x) + p1 * (y1a.x + y1b.x + b1v.x);
  float v1 = vx.y + p0 * (y0a.y + y0b.y + b0v.y) + p1 * (y1a.y + y1b.y + b1v.y);
  float v2 = vx.z + p0 * (y0a.z + y0b.z + b0v.z) + p1 * (y1a.z + y1b.z + b1v.z);
  float v3 = vx.w + p0 * (y0a.w + y0b.w + b0v.w) + p1 * (y1a.w + y1b.w + b1v.w);
  float s = v0 + v1 + v2 + v3;
  float s2 = v0 * v0 + v1 * v1 + v2 * v2 + v3 * v3;
  __shared__ float sa[4], sb[4];
  for (int o = 32; o; o >>= 1) { s += __shfl_down(s, o); s2 += __shfl_down(s2, o); }
  int lane = tid & 63, w = tid >> 6;
  if (lane == 0) { sa[w] = s; sb[w] = s2; }
  __syncthreads();
  s = sa[0] + sa[1] + sa[2] + sa[3];
  s2 = sb[0] + sb[1] + sb[2] + sb[3];
  float mu = s * (1.f / DMODEL);
  float var = s2 * (1.f / DMODEL) - mu * mu;
  float rs = rsqrtf(var + LN_EPS);
  float4 gg = ((const float4*)g)[tid];
  float4 bv = ((const float4*)bb)[tid];
  float4 o;
  o.x = (v0 - mu) * rs * gg.x + bv.x;
  o.y = (v1 - mu) * rs * gg.y + bv.y;
  o.z = (v2 - mu) * rs * gg.z + bv.z;
  o.w = (v3 - mu) * rs * gg.w + bv.w;
  ((float4*)(out + (long)t * DMODEL))[tid] = o;
}

// ---------------------------------------------------------------------------
extern "C" void kernel_launch(void* const* d_in, const int* in_sizes, int n_in,
                              void* d_out, int out_size, void* d_ws, size_t ws_size,
                              hipStream_t stream) {
  const float* src  = (const float*)d_in[0];
  const float* inw  = (const float*)d_in[1];
  const float* inb  = (const float*)d_in[2];
  const float* outw = (const float*)d_in[3];
  const float* outb = (const float*)d_in[4];
  const float* gw   = (const float*)d_in[5];
  const float* gb   = (const float*)d_in[6];
  const float* w1   = (const float*)d_in[7];
  const float* b1   = (const float*)d_in[8];
  const float* w2   = (const float*)d_in[9];
  const float* b2   = (const float*)d_in[10];
  const float* g1   = (const float*)d_in[11];
  const float* bb1  = (const float*)d_in[12];
  const float* g2   = (const float*)d_in[13];
  const float* bb2  = (const float*)d_in[14];
  float* out = (float*)d_out;

  char* w = (char*)d_ws;
  auto alloc = [&](size_t bytes) {
    char* p = w;
    w += (bytes + 255) & ~(size_t)255;
    return p;
  };

  int*   cnt     = (int*)alloc(8 * 4);
  int*   offp    = (int*)alloc(8 * 4);
  float* usage   = (float*)alloc(8 * 4);
  int*   tok_list= (int*)alloc((size_t)NEXP * 2048 * 4);
  int*   tk_e    = (int*)alloc((size_t)2 * T_TOK * 4);
  int*   tk_pos  = (int*)alloc((size_t)2 * T_TOK * 4);
  float* tk_prob = (float*)alloc((size_t)2 * T_TOK * 4);

  u16* src_bf  = (u16*)alloc((size_t)T_TOK * DMODEL * 2);
  u16* inw_bf  = (u16*)alloc((size_t)3 * DMODEL * DMODEL * 2);
  u16* outw_bf = (u16*)alloc((size_t)DMODEL * DMODEL * 2);
  u16* w1_bf   = (u16*)alloc((size_t)NEXP * FDIM * DMODEL * 2);
  u16* w2_bf   = (u16*)alloc((size_t)NEXP * DMODEL * FDIM * 2);
  u16* qkv_bf  = (u16*)alloc((size_t)T_TOK * 3 * DMODEL * 2);
  u16* vt_bf   = (u16*)alloc((size_t)T_TOK * DMODEL * 2);    // (B,H,HD,S)
  u16* o2_bf   = (u16*)alloc((size_t)T_TOK * DMODEL * 2);    // (B,S,D)
  float* attn_p= (float*)alloc((size_t)2 * T_TOK * DMODEL * 4);  // 2 split-K partials
  float* x_f   = (float*)alloc((size_t)T_TOK * DMODEL * 4);
  u16* x_bf    = (u16*)alloc((size_t)T_TOK * DMODEL * 2);
  u16* xg_bf   = (u16*)alloc((size_t)2 * T_TOK * DMODEL * 2);
  u16* h_bf    = (u16*)alloc((size_t)2 * T_TOK * FDIM * 2);
  float* y_f   = (float*)alloc((size_t)4 * T_TOK * DMODEL * 4);  // 2 K-halves
  (void)ws_size; (void)n_in; (void)in_sizes; (void)out_size;

  hipMemsetAsync(cnt, 0, 3 * 256, stream);  // cnt, offp, usage regions

  // bf16 conversions
  cvt_small<<<(T_TOK * DMODEL / 4 + 255) / 256, 256, 0, stream>>>(src, src_bf, T_TOK * DMODEL / 4);
  cvt_small<<<(3 * DMODEL * DMODEL / 4 + 255) / 256, 256, 0, stream>>>(inw, inw_bf, 3L * DMODEL * DMODEL / 4);
  cvt_small<<<(DMODEL * DMODEL / 4 + 255) / 256, 256, 0, stream>>>(outw, outw_bf, (long)DMODEL * DMODEL / 4);
  cvt_w1<<<(int)((long)NEXP * FDIM * DMODEL / 4 / 256), 256, 0, stream>>>(w1, w1_bf, (long)NEXP * FDIM * DMODEL / 4);
  cvt_w2<<<(int)((long)NEXP * DMODEL * FDIM / 4 / 256), 256, 0, stream>>>(w2, w2_bf, (long)NEXP * DMODEL * FDIM / 4);

  // QKV projection: (2048x1024) @ (3072x1024)^T + b -> bf16
  k_qkv<<<dim3(24, 32), 256, 0, stream>>>(src_bf, inw_bf, qkv_bf, inb);

  transpose_v<<<dim3(16, 32), 256, 0, stream>>>(qkv_bf, vt_bf);

  // fused flash attention -> o2_bf (B,S,D)
  fused_attn<<<dim3(8, 32), 256, 0, stream>>>(qkv_bf, vt_bf, o2_bf);

  // output projection, split-K=2 -> two fp32 partials (bias folded into add_ln)
  k_outp<<<dim3(8, 32, 2), 256, 0, stream>>>(o2_bf, outw_bf, attn_p);

  // residual + out-proj bias + LN1
  add_ln<<<T_TOK, 256, 0, stream>>>(src, attn_p, attn_p + (long)T_TOK * DMODEL,
                                    outb, g1, bb1, x_f, x_bf);

  // gate + routing
  gate_kernel<<<T_TOK / 4, 256, 0, stream>>>(x_f, gw, gb, cnt, tok_list,
                                             tk_e, tk_pos, tk_prob, usage);
  finalize_gate<<<1, 64, 0, stream>>>(cnt, offp, usage, out + (long)T_TOK * DMODEL);

  gather_x<<<dim3(2048, 8), 256, 0, stream>>>(x_bf, cnt, offp, tok_list, xg_bf);

  // FFN1 (grouped, gelu fused) -> bf16
  k_ffn1<<<dim3(32, 16, 8), 256, 0, stream>>>(xg_bf, w1_bf, h_bf, b1, cnt, offp);

  // FFN2 (grouped, BM=128, split-K=2) -> 2 fp32 partial buffers
  k_ffn2<<<dim3(8, 16, 16), 256, 0, stream>>>(h_bf, w2_bf, y_f, cnt, offp);

  // combine (partials + b2) + residual + LN2 -> output
  moe_ln2<<<T_TOK, 256, 0, stream>>>(x_f, y_f, b2, offp, tk_e, tk_pos, tk_prob,
                                     g2, bb2, out);
}

// Round 7
// 634.010 us; speedup vs baseline: 1.2657x; 1.0186x over previous
//
#include <hip/hip_runtime.h>
#include <stdint.h>
#include <stddef.h>

// Problem constants
#define T_TOK 2048     // B*S tokens
#define DMODEL 1024
#define NHEAD 16
#define HDIM 64
#define NEXP 8
#define FDIM 4096
#define SLEN 1024
#define NBATCH 2
#define LN_EPS 1e-5f

typedef unsigned short u16;
typedef __attribute__((ext_vector_type(8))) short s16x8;   // 8 bf16 MFMA frag
typedef __attribute__((ext_vector_type(4))) float f32x4;   // MFMA accumulator
typedef __attribute__((ext_vector_type(4))) unsigned short u16x4;
typedef __attribute__((ext_vector_type(8))) unsigned short u16x8;

typedef __attribute__((address_space(1))) void gvoid;      // global
typedef __attribute__((address_space(3))) void lvoid;      // LDS

__device__ __forceinline__ u16 f2bf(float x) {
  union { float f; unsigned int u; } v; v.f = x;
  unsigned int r = v.u + 0x7fffu + ((v.u >> 16) & 1u);  // RNE
  return (u16)(r >> 16);
}

// async global->LDS, 16B/lane. Dest is wave-uniform base; HW adds lane*16.
__device__ __forceinline__ void gl_lds16(const u16* g, u16* lds_base) {
  __builtin_amdgcn_global_load_lds((gvoid*)g, (lvoid*)lds_base, 16, 0, 0);
}

// fast GELU: 0.5v(1+tanh(0.79788456(v+0.044715v^3))) == v*sigmoid(2u).
// ~7 VALU ops vs ~25 for erff; |err| < 1e-3 << absmax budget.
__device__ __forceinline__ float gelu_fast(float v) {
  float vv = v * v;
  float e = __expf(v * (-1.5957691216f - 0.0713548162f * vv));
  return v * __builtin_amdgcn_rcpf(1.f + e);
}

// ---------------------------------------------------------------------------
// fp32 -> bf16 convert (named clones for profile attribution)
// ---------------------------------------------------------------------------
__device__ __forceinline__ void cvt_body(const float* __restrict__ x,
                                         u16* __restrict__ y, long n4) {
  long i = (long)blockIdx.x * 256 + threadIdx.x;
  if (i >= n4) return;
  float4 v = ((const float4*)x)[i];
  u16x4 o;
  o[0] = f2bf(v.x); o[1] = f2bf(v.y); o[2] = f2bf(v.z); o[3] = f2bf(v.w);
  ((u16x4*)y)[i] = o;
}
__global__ __launch_bounds__(256) void cvt_small(const float* x, u16* y, long n4) { cvt_body(x, y, n4); }
__global__ __launch_bounds__(256) void cvt_w1(const float* x, u16* y, long n4) { cvt_body(x, y, n4); }
__global__ __launch_bounds__(256) void cvt_w2(const float* x, u16* y, long n4) { cvt_body(x, y, n4); }

// ---------------------------------------------------------------------------
// Pipelined GEMM body: C = act(A @ B^T + bias), BN=128, BM in {64,128}.
// Double-buffered LDS, prefetch distance 2, raw s_barrier + partial vmcnt
// waits (never vmcnt(0) mid-loop).
// Staging addresses are persistent pointers advanced by 64 elem per K-step
// (init once) — removes the per-iteration 64-bit addr chains that showed as
// VALUBusy 43% vs MfmaUtil 17% on k_ffn1.
// Epilogue: restage output tile through LDS for full-128B-line stores.
// ---------------------------------------------------------------------------
template<int BM, int OUTBF, int DOGELU>
__device__ __forceinline__ void gemm_body(
    const u16* __restrict__ A, long lda,
    const u16* __restrict__ Bp, long ldb,
    char* __restrict__ C, long ldc,
    const float* __restrict__ bias,
    int Mloc, int k0start, int Kc, int m0, int n0) {
  constexpr int AS_BYTES = 2 * BM * 64 * 2;
  constexpr int SMEM_BYTES = AS_BYTES + 2 * 128 * 64 * 2;   // As + Bs
  __shared__ __align__(16) char smem[SMEM_BYTES];
  u16 (*As)[BM][64]  = reinterpret_cast<u16(*)[BM][64]>(smem);
  u16 (*Bs)[128][64] = reinterpret_cast<u16(*)[128][64]>(smem + AS_BYTES);

  constexpr int SM = BM / 32;           // M-frags per wave
  constexpr int NPA = BM / 32;          // A staging insts per wave per tile
  constexpr int LPI = NPA + 4;          // total gl_lds insts per wave per tile

  int tid = threadIdx.x;
  int lane = tid & 63, w = tid >> 6;
  int lrow = lane >> 3;                 // 0..7
  int sg8 = ((lane & 7) ^ lrow) * 8;    // XOR-swizzled source granule
  int q = lane >> 4, rr = lane & 15;
  int wm = (w & 1) * (BM / 2), wn = (w >> 1) * 64;
  int NIT = Kc >> 6;

  // persistent staging pointers (advanced 64 elems per issue call)
  const u16* aP[NPA];
  const u16* bP[4];
#pragma unroll
  for (int p = 0; p < NPA; p++) {
    int gr = m0 + p * 32 + w * 8 + lrow;
    if (gr > Mloc - 1) gr = Mloc - 1;   // M-tail clamp
    aP[p] = A + (long)gr * lda + k0start + sg8;
  }
#pragma unroll
  for (int p = 0; p < 4; p++)
    bP[p] = Bp + (long)(n0 + p * 32 + w * 8 + lrow) * ldb + k0start + sg8;

  auto issue = [&](int b) {
#pragma unroll
    for (int p = 0; p < NPA; p++) {
      gl_lds16(aP[p], &As[b][p * 32 + w * 8][0]);
      aP[p] += 64;
    }
#pragma unroll
    for (int p = 0; p < 4; p++) {
      gl_lds16(bP[p], &Bs[b][p * 32 + w * 8][0]);
      bP[p] += 64;
    }
  };

  f32x4 acc[SM][4];
  for (int i = 0; i < SM; i++)
    for (int j = 0; j < 4; j++)
      for (int r = 0; r < 4; r++) acc[i][j][r] = 0.f;

  issue(0);
  if (NIT > 1) issue(1);

  int slot0 = ((q ^ (rr & 7)) * 8);           // kk=0 swizzled slot
  int slot1 = (((4 + q) ^ (rr & 7)) * 8);     // kk=1

  for (int kt = 0; kt < NIT; kt++) {
    int b = kt & 1;
    // wait for tile kt only; tile kt+1's LPI loads remain outstanding
    if (kt + 1 < NIT)
      asm volatile("s_waitcnt vmcnt(%0)" :: "i"(LPI) : "memory");
    else
      asm volatile("s_waitcnt vmcnt(0)" ::: "memory");
    asm volatile("s_barrier" ::: "memory");

    s16x8 a0[SM], a1[SM], b0[4], b1[4];
    for (int i = 0; i < SM; i++) {
      a0[i] = *(const s16x8*)&As[b][wm + i * 16 + rr][slot0];
      a1[i] = *(const s16x8*)&As[b][wm + i * 16 + rr][slot1];
    }
    for (int j = 0; j < 4; j++) {
      b0[j] = *(const s16x8*)&Bs[b][wn + j * 16 + rr][slot0];
      b1[j] = *(const s16x8*)&Bs[b][wn + j * 16 + rr][slot1];
    }
    asm volatile("s_waitcnt lgkmcnt(0)" ::: "memory");  // frags in regs
    asm volatile("s_barrier" ::: "memory");             // all waves done reading buf b
    if (kt + 2 < NIT) issue(b);                         // overwrite buf b (visible at kt+2)

    for (int i = 0; i < SM; i++)
      for (int j = 0; j < 4; j++) {
        acc[i][j] = __builtin_amdgcn_mfma_f32_16x16x32_bf16(a0[i], b0[j], acc[i][j], 0, 0, 0);
        acc[i][j] = __builtin_amdgcn_mfma_f32_16x16x32_bf16(a1[i], b1[j], acc[i][j], 0, 0, 0);
      }
  }

  // ---- epilogue: stage through LDS, then full-line coalesced stores ----
  u16*   Cu = (u16*)smem;     // [BM][128] bf16 tile
  float* Cf = (float*)smem;   // [BM][128] fp32 tile
  for (int i = 0; i < SM; i++)
    for (int j = 0; j < 4; j++) {
      int col = wn + j * 16 + rr;
      float bv = bias ? bias[n0 + col] : 0.f;
      for (int r = 0; r < 4; r++) {
        int row = wm + i * 16 + q * 4 + r;
        float v = acc[i][j][r] + bv;
        if (DOGELU) v = gelu_fast(v);
        if (OUTBF) Cu[row * 128 + col] = f2bf(v);
        else       Cf[row * 128 + col] = v;
      }
    }
  __syncthreads();
  if (OUTBF) {
    for (int p = 0; p < BM / 16; p++) {
      int row = p * 16 + (tid >> 4);
      int co  = (tid & 15) * 8;
      if (m0 + row < Mloc) {
        u16x8 vv = *(const u16x8*)&Cu[row * 128 + co];
        *(u16x8*)((u16*)C + (long)(m0 + row) * ldc + n0 + co) = vv;
      }
    }
  } else {
    for (int p = 0; p < BM / 8; p++) {
      int row = p * 8 + (tid >> 5);
      int co  = (tid & 31) * 4;
      if (m0 + row < Mloc) {
        float4 vv = *(const float4*)&Cf[row * 128 + co];
        *(float4*)((float*)C + (long)(m0 + row) * ldc + n0 + co) = vv;
      }
    }
  }
}

// ---- named GEMM wrappers (R0 grids: balanced round-robin across XCDs) -----
// QKV: BM=128 (2x MFMA per barrier vs BM=64)
__global__ __launch_bounds__(256) void k_qkv(const u16* __restrict__ A,
                                             const u16* __restrict__ B,
                                             u16* __restrict__ C,
                                             const float* __restrict__ bias) {
  gemm_body<128, 1, 0>(A, DMODEL, B, DMODEL, (char*)C, 3 * DMODEL, bias,
                       T_TOK, 0, DMODEL, blockIdx.y * 128, blockIdx.x * 128);
}

// out-projection, split-K=2: z picks K-half, writes partial buffer z
__global__ __launch_bounds__(256) void k_outp(const u16* __restrict__ A,
                                              const u16* __restrict__ B,
                                              float* __restrict__ Cpart) {
  int z = blockIdx.z;
  char* C = (char*)(Cpart + (long)z * T_TOK * DMODEL);
  gemm_body<64, 0, 0>(A, DMODEL, B, DMODEL, C, DMODEL, nullptr,
                      T_TOK, z * 512, 512, blockIdx.y * 64, blockIdx.x * 128);
}

__global__ __launch_bounds__(256) void k_ffn1(const u16* __restrict__ Ag,
                                              const u16* __restrict__ Bg,
                                              u16* __restrict__ Cg,
                                              const float* __restrict__ biasg,
                                              const int* __restrict__ cntp,
                                              const int* __restrict__ offp) {
  int z = blockIdx.z;
  int Mloc = cntp[z];
  int m0 = blockIdx.y * 128;
  if (m0 >= Mloc) return;
  long o = offp[z];
  gemm_body<128, 1, 1>(Ag + o * DMODEL, DMODEL,
                       Bg + (long)z * FDIM * DMODEL, DMODEL,
                       (char*)(Cg + o * FDIM), FDIM,
                       biasg + (long)z * FDIM,
                       Mloc, 0, DMODEL, m0, blockIdx.x * 128);
}

// FFN2: BM=128 + split-K=2. Bias + partial combine moved to moe_ln2.
__global__ __launch_bounds__(256) void k_ffn2(const u16* __restrict__ Ag,
                                              const u16* __restrict__ Bg,
                                              float* __restrict__ Cpart,
                                              const int* __restrict__ cntp,
                                              const int* __restrict__ offp) {
  int zz = blockIdx.z;                 // 0..15 = kh*8 + expert
  int z = zz & 7, kh = zz >> 3;
  int Mloc = cntp[z];
  int m0 = blockIdx.y * 128;
  if (m0 >= Mloc) return;
  long o = offp[z];
  float* C = Cpart + (long)kh * 2 * T_TOK * DMODEL;
  gemm_body<128, 0, 0>(Ag + o * FDIM, FDIM,
                       Bg + (long)z * DMODEL * FDIM, FDIM,
                       (char*)(C + o * DMODEL), DMODEL,
                       nullptr,
                       Mloc, kh * 2048, 2048, m0, blockIdx.x * 128);
}

// ---------------------------------------------------------------------------
// V part of qkv -> Vt (B,H,HD,S) bf16 (transposed via LDS tile)
// ---------------------------------------------------------------------------
__global__ __launch_bounds__(256) void transpose_v(const u16* __restrict__ qkv,
                                                   u16* __restrict__ vt) {
  __shared__ u16 tile[64][65];
  int s0 = blockIdx.x * 64, bh = blockIdx.y;
  int b = bh >> 4, h = bh & 15;
  int r = threadIdx.x >> 3, c = (threadIdx.x & 7) * 8;
  for (int p = 0; p < 64; p += 32) {
    u16x8 v = *(const u16x8*)&qkv[(long)(b * SLEN + s0 + p + r) * 3072 + 2048 + h * 64 + c];
    for (int j = 0; j < 8; j++) tile[p + r][c + j] = v[j];
  }
  __syncthreads();
  for (int p = 0; p < 64; p += 32) {
    int d = p + r;
    u16x8 v;
    for (int j = 0; j < 8; j++) v[j] = tile[c + j][d];
    *(u16x8*)&vt[((long)bh * 64 + d) * SLEN + s0 + c] = v;
  }
}

// ---------------------------------------------------------------------------
// Fused flash attention: per (q-tile 128, b*h) block. Writes (B,S,D) bf16.
// K/V double-buffered with DMA prefetch; ONE barrier per K-tile.
// ---------------------------------------------------------------------------
__global__ __launch_bounds__(256) void fused_attn(const u16* __restrict__ qkv,
                                                  const u16* __restrict__ vt,
                                                  u16* __restrict__ o2) {
  __shared__ u16 Qs[128][64];      // swizzled
  __shared__ u16 Ks[2][64][64];    // swizzled, double-buffered
  __shared__ u16 Vs[2][64][64];    // swizzled (rows = head-dim d, cols = keys)
  __shared__ u16 Ps[128][72];      // padded

  int qt = blockIdx.x, bh = blockIdx.y;
  int b = bh >> 4, h = bh & 15;
  const u16* base = qkv + (long)b * SLEN * 3072 + h * 64;
  const u16* vbase = vt + (long)bh * HDIM * SLEN;

  int tid = threadIdx.x, lane = tid & 63, w = tid >> 6;
  int lrow = lane >> 3;
  int sg8 = ((lane & 7) ^ lrow) * 8;
  int q = lane >> 4, rr = lane & 15;
  int wm = w * 32;

  auto issue_kv = [&](int kt, int bf) {
    for (int p = 0; p < 2; p++) {
      int rb = p * 32 + w * 8;
      gl_lds16(base + (long)(kt * 64 + rb + lrow) * 3072 + 1024 + sg8, &Ks[bf][rb][0]);
      gl_lds16(vbase + (long)(rb + lrow) * SLEN + kt * 64 + sg8, &Vs[bf][rb][0]);
    }
  };

  // stage Q once + first K/V tile
  for (int p = 0; p < 4; p++) {
    int rb = p * 32 + w * 8;
    gl_lds16(base + (long)(qt * 128 + rb + lrow) * 3072 + sg8, &Qs[rb][0]);
  }
  issue_kv(0, 0);

  f32x4 O[2][4];
  float mi[2][4], li[2][4];
  for (int i = 0; i < 2; i++)
    for (int r = 0; r < 4; r++) { mi[i][r] = -1e30f; li[i][r] = 0.f; }
  for (int i = 0; i < 2; i++)
    for (int jn = 0; jn < 4; jn++)
      for (int r = 0; r < 4; r++) O[i][jn][r] = 0.f;

  for (int kt = 0; kt < 16; kt++) {
    int bf = kt & 1;
    asm volatile("s_waitcnt vmcnt(0)" ::: "memory");   // own DMA for tile kt landed
    asm volatile("s_barrier" ::: "memory");            // all waves' DMA landed; prev iter done
    if (kt + 1 < 16) issue_kv(kt + 1, bf ^ 1);         // prefetch overlaps full iteration

    // S = Q @ K^T
    f32x4 S[2][4];
    for (int i = 0; i < 2; i++)
      for (int j = 0; j < 4; j++)
        for (int r = 0; r < 4; r++) S[i][j][r] = 0.f;
    for (int ks = 0; ks < 2; ks++) {
      int slot = (((ks * 4 + q) ^ (rr & 7)) * 8);
      s16x8 aq0 = *(const s16x8*)&Qs[wm + rr][slot];
      s16x8 aq1 = *(const s16x8*)&Qs[wm + 16 + rr][slot];
      for (int j = 0; j < 4; j++) {
        s16x8 bk = *(const s16x8*)&Ks[bf][j * 16 + rr][slot];
        S[0][j] = __builtin_amdgcn_mfma_f32_16x16x32_bf16(aq0, bk, S[0][j], 0, 0, 0);
        S[1][j] = __builtin_amdgcn_mfma_f32_16x16x32_bf16(aq1, bk, S[1][j], 0, 0, 0);
      }
    }

    // online softmax
    for (int i = 0; i < 2; i++) {
      for (int r = 0; r < 4; r++) {
        float mx = -1e30f;
        for (int j = 0; j < 4; j++) mx = fmaxf(mx, S[i][j][r]);
        for (int o = 1; o < 16; o <<= 1) mx = fmaxf(mx, __shfl_xor(mx, o));
        mx *= 0.125f;
        float mnew = fmaxf(mi[i][r], mx);
        float al = __expf(mi[i][r] - mnew);
        mi[i][r] = mnew;
        float ps = 0.f;
        for (int j = 0; j < 4; j++) {
          float e = __expf(S[i][j][r] * 0.125f - mnew);
          S[i][j][r] = e;
          ps += e;
        }
        for (int o = 1; o < 16; o <<= 1) ps += __shfl_xor(ps, o);
        li[i][r] = li[i][r] * al + ps;
        for (int jn = 0; jn < 4; jn++) O[i][jn][r] *= al;
      }
    }

    // P -> LDS (wave-private band: rows wm..wm+31)
    for (int i = 0; i < 2; i++)
      for (int j = 0; j < 4; j++)
        for (int r = 0; r < 4; r++)
          Ps[wm + i * 16 + q * 4 + r][j * 16 + rr] = f2bf(S[i][j][r]);

    // O += P @ V  (Ps reads are same-wave band; compiler orders ds ops)
    for (int ks = 0; ks < 2; ks++) {
      s16x8 ap0 = *(const s16x8*)&Ps[wm + rr][ks * 32 + q * 8];
      s16x8 ap1 = *(const s16x8*)&Ps[wm + 16 + rr][ks * 32 + q * 8];
      int slot = (((ks * 4 + q) ^ (rr & 7)) * 8);
      for (int jn = 0; jn < 4; jn++) {
        s16x8 bv = *(const s16x8*)&Vs[bf][jn * 16 + rr][slot];
        O[0][jn] = __builtin_amdgcn_mfma_f32_16x16x32_bf16(ap0, bv, O[0][jn], 0, 0, 0);
        O[1][jn] = __builtin_amdgcn_mfma_f32_16x16x32_bf16(ap1, bv, O[1][jn], 0, 0, 0);
      }
    }
  }

  // ---- epilogue: restage O through LDS (reuse Ps), full-line stores ----
  __syncthreads();                      // all PV ds_reads of Ps done (cross-band alias)
  u16* Pf = &Ps[0][0];                  // flat [128][64]
  for (int i = 0; i < 2; i++)
    for (int r = 0; r < 4; r++) {
      float inv = 1.f / li[i][r];
      int row = wm + i * 16 + q * 4 + r;
      for (int jn = 0; jn < 4; jn++)
        Pf[row * 64 + jn * 16 + rr] = f2bf(O[i][jn][r] * inv);
    }
  __syncthreads();
  for (int p = 0; p < 4; p++) {
    int row = p * 32 + (tid >> 3);
    int co  = (tid & 7) * 8;
    u16x8 vv = *(const u16x8*)&Pf[row * 64 + co];
    int s = qt * 128 + row;
    *(u16x8*)&o2[((long)(b * SLEN + s)) * DMODEL + h * 64 + co] = vv;
  }
}

// ---------------------------------------------------------------------------
// residual add (+out-proj bias, 2 split-K partials) + LayerNorm -> fp32+bf16
// ---------------------------------------------------------------------------
__global__ __launch_bounds__(256) void add_ln(const float* __restrict__ a,
                                              const float* __restrict__ p0,
                                              const float* __restrict__ p1,
                                              const float* __restrict__ ob,
                                              const float* __restrict__ g,
                                              const float* __restrict__ bb,
                                              float* __restrict__ xf, u16* __restrict__ xb) {
  int t = blockIdx.x, tid = threadIdx.x;
  float4 va = ((const float4*)(a + (long)t * DMODEL))[tid];
  float4 v0v = ((const float4*)(p0 + (long)t * DMODEL))[tid];
  float4 v1v = ((const float4*)(p1 + (long)t * DMODEL))[tid];
  float4 vo = ((const float4*)ob)[tid];
  float v0 = va.x + v0v.x + v1v.x + vo.x;
  float v1 = va.y + v0v.y + v1v.y + vo.y;
  float v2 = va.z + v0v.z + v1v.z + vo.z;
  float v3 = va.w + v0v.w + v1v.w + vo.w;
  float s = v0 + v1 + v2 + v3;
  float s2 = v0 * v0 + v1 * v1 + v2 * v2 + v3 * v3;
  __shared__ float sa[4], sb[4];
  for (int o = 32; o; o >>= 1) { s += __shfl_down(s, o); s2 += __shfl_down(s2, o); }
  int lane = tid & 63, w = tid >> 6;
  if (lane == 0) { sa[w] = s; sb[w] = s2; }
  __syncthreads();
  s = sa[0] + sa[1] + sa[2] + sa[3];
  s2 = sb[0] + sb[1] + sb[2] + sb[3];
  float mu = s * (1.f / DMODEL);
  float var = s2 * (1.f / DMODEL) - mu * mu;
  float rs = rsqrtf(var + LN_EPS);
  float4 gg = ((const float4*)g)[tid];
  float4 bv = ((const float4*)bb)[tid];
  float4 o;
  o.x = (v0 - mu) * rs * gg.x + bv.x;
  o.y = (v1 - mu) * rs * gg.y + bv.y;
  o.z = (v2 - mu) * rs * gg.z + bv.z;
  o.w = (v3 - mu) * rs * gg.w + bv.w;
  ((float4*)(xf + (long)t * DMODEL))[tid] = o;
  u16x4 obv;
  obv[0] = f2bf(o.x); obv[1] = f2bf(o.y); obv[2] = f2bf(o.z); obv[3] = f2bf(o.w);
  ((u16x4*)(xb + (long)t * DMODEL))[tid] = obv;
}

// ---------------------------------------------------------------------------
// Gate: logits, full softmax (usage/aux), top-2 routing lists
// ---------------------------------------------------------------------------
__global__ __launch_bounds__(256) void gate_kernel(
    const float* __restrict__ xf, const float* __restrict__ gw, const float* __restrict__ gb,
    int* __restrict__ cnt, int* __restrict__ tok_list,
    int* __restrict__ tk_e, int* __restrict__ tk_pos, float* __restrict__ tk_prob,
    float* __restrict__ usage) {
  int wid = threadIdx.x >> 6, lane = threadIdx.x & 63;
  int t = blockIdx.x * 4 + wid;
  float xv[16];
  for (int j = 0; j < 16; j++) xv[j] = xf[(long)t * DMODEL + j * 64 + lane];
  float l[8];
  for (int e = 0; e < 8; e++) {
    float d = 0.f;
    for (int j = 0; j < 16; j++) d += xv[j] * gw[e * DMODEL + j * 64 + lane];
    for (int o = 32; o; o >>= 1) d += __shfl_down(d, o);
    l[e] = d;  // valid on lane 0 only
  }
  __shared__ float us[8];
  if (threadIdx.x < 8) us[threadIdx.x] = 0.f;
  __syncthreads();
  if (lane == 0) {
    float mx = -1e30f;
    for (int e = 0; e < 8; e++) { l[e] += gb[e]; mx = fmaxf(mx, l[e]); }
    float ex[8], sum = 0.f;
    for (int e = 0; e < 8; e++) { ex[e] = expf(l[e] - mx); sum += ex[e]; }
    float inv = 1.f / sum;
    for (int e = 0; e < 8; e++) atomicAdd(&us[e], ex[e] * inv);
    int i1 = 0;
    for (int e = 1; e < 8; e++) if (l[e] > l[i1]) i1 = e;
    int i2 = (i1 == 0) ? 1 : 0;
    for (int e = 0; e < 8; e++) if (e != i1 && l[e] > l[i2]) i2 = e;
    float bb = expf(l[i2] - l[i1]);
    float p1 = 1.f / (1.f + bb), p2 = bb / (1.f + bb);
    int pos1 = atomicAdd(&cnt[i1], 1);
    tok_list[i1 * 2048 + pos1] = t;
    tk_e[2 * t] = i1; tk_pos[2 * t] = pos1; tk_prob[2 * t] = p1;
    int pos2 = atomicAdd(&cnt[i2], 1);
    tok_list[i2 * 2048 + pos2] = t;
    tk_e[2 * t + 1] = i2; tk_pos[2 * t + 1] = pos2; tk_prob[2 * t + 1] = p2;
  }
  __syncthreads();
  if (threadIdx.x < 8) atomicAdd(&usage[threadIdx.x], us[threadIdx.x]);
}

__global__ void finalize_gate(const int* __restrict__ cnt, int* __restrict__ offp,
                              const float* __restrict__ usage, float* __restrict__ aux_out) {
  if (threadIdx.x == 0) {
    int o = 0;
    for (int e = 0; e < 8; e++) { offp[e] = o; o += cnt[e]; }
    float s = 0.f;
    for (int e = 0; e < 8; e++) { float u = usage[e] * (1.f / T_TOK); s += u * u; }
    aux_out[0] = (float)NEXP * s;
  }
}

// gather x rows per expert into compact buffer
__global__ __launch_bounds__(256) void gather_x(const u16* __restrict__ xb,
                                                const int* __restrict__ cnt,
                                                const int* __restrict__ offp,
                                                const int* __restrict__ tok_list,
                                                u16* __restrict__ xg) {
  int e = blockIdx.y, i = blockIdx.x;
  if (i >= cnt[e]) return;
  int t = tok_list[e * 2048 + i];
  long j = offp[e] + i;
  ((uint2*)(xg + j * DMODEL))[threadIdx.x] =
      ((const uint2*)(xb + (long)t * DMODEL))[threadIdx.x];
}

// weighted expert-output combine (2 split-K partials + b2 bias) + residual
// + LN2 -> final output
__global__ __launch_bounds__(256) void moe_ln2(
    const float* __restrict__ xf, const float* __restrict__ y,
    const float* __restrict__ b2g,
    const int* __restrict__ offp, const int* __restrict__ tk_e,
    const int* __restrict__ tk_pos, const float* __restrict__ tk_prob,
    const float* __restrict__ g, const float* __restrict__ bb, float* __restrict__ out) {
  const long HALF = (long)2 * T_TOK * DMODEL;
  int t = blockIdx.x, tid = threadIdx.x;
  int e0 = tk_e[2 * t], e1 = tk_e[2 * t + 1];
  long j0 = (long)offp[e0] + tk_pos[2 * t];
  long j1 = (long)offp[e1] + tk_pos[2 * t + 1];
  float p0 = tk_prob[2 * t], p1 = tk_prob[2 * t + 1];
  float4 vx = ((const float4*)(xf + (long)t * DMODEL))[tid];
  float4 y0a = ((const float4*)(y + j0 * DMODEL))[tid];
  float4 y0b = ((const float4*)(y + HALF + j0 * DMODEL))[tid];
  float4 y1a = ((const float4*)(y + j1 * DMODEL))[tid];
  float4 y1b = ((const float4*)(y + HALF + j1 * DMODEL))[tid];
  float4 b0v = ((const float4*)(b2g + (long)e0 * DMODEL))[tid];
  float4 b1v = ((const float4*)(b2g + (long)e1 * DMODEL))[tid];
  float v0 = vx.x + p0 * (y0a.x + y0b.x + b0v.x) + p1 * (y1a.x + y1b.x + b1v.x);
  float v1 = vx.y + p0 * (y0a.y + y0b.y + b0v.y) + p1 * (y1a.y + y1b.y + b1v.y);
  float v2 = vx.z + p0 * (y0a.z + y0b.z + b0v.z) + p1 * (y1a.z + y1b.z + b1v.z);
  float v3 = vx.w + p0 * (y0a.w + y0b.w + b0v.w) + p1 * (y1a.w + y1b.w + b1v.w);
  float s = v0 + v1 + v2 + v3;
  float s2 = v0 * v0 + v1 * v1 + v2 * v2 + v3 * v3;
  __shared__ float sa[4], sb[4];
  for (int o = 32; o; o >>= 1) { s += __shfl_down(s, o); s2 += __shfl_down(s2, o); }
  int lane = tid & 63, w = tid >> 6;
  if (lane == 0) { sa[w] = s; sb[w] = s2; }
  __syncthreads();
  s = sa[0] + sa[1] + sa[2] + sa[3];
  s2 = sb[0] + sb[1] + sb[2] + sb[3];
  float mu = s * (1.f / DMODEL);
  float var = s2 * (1.f / DMODEL) - mu * mu;
  float rs = rsqrtf(var + LN_EPS);
  float4 gg = ((const float4*)g)[tid];
  float4 bv = ((const float4*)bb)[tid];
  float4 o;
  o.x = (v0 - mu) * rs * gg.x + bv.x;
  o.y = (v1 - mu) * rs * gg.y + bv.y;
  o.z = (v2 - mu) * rs * gg.z + bv.z;
  o.w = (v3 - mu) * rs * gg.w + bv.w;
  ((float4*)(out + (long)t * DMODEL))[tid] = o;
}

// ---------------------------------------------------------------------------
extern "C" void kernel_launch(void* const* d_in, const int* in_sizes, int n_in,
                              void* d_out, int out_size, void* d_ws, size_t ws_size,
                              hipStream_t stream) {
  const float* src  = (const float*)d_in[0];
  const float* inw  = (const float*)d_in[1];
  const float* inb  = (const float*)d_in[2];
  const float* outw = (const float*)d_in[3];
  const float* outb = (const float*)d_in[4];
  const float* gw   = (const float*)d_in[5];
  const float* gb   = (const float*)d_in[6];
  const float* w1   = (const float*)d_in[7];
  const float* b1   = (const float*)d_in[8];
  const float* w2   = (const float*)d_in[9];
  const float* b2   = (const float*)d_in[10];
  const float* g1   = (const float*)d_in[11];
  const float* bb1  = (const float*)d_in[12];
  const float* g2   = (const float*)d_in[13];
  const float* bb2  = (const float*)d_in[14];
  float* out = (float*)d_out;

  char* w = (char*)d_ws;
  auto alloc = [&](size_t bytes) {
    char* p = w;
    w += (bytes + 255) & ~(size_t)255;
    return p;
  };

  int*   cnt     = (int*)alloc(8 * 4);
  int*   offp    = (int*)alloc(8 * 4);
  float* usage   = (float*)alloc(8 * 4);
  int*   tok_list= (int*)alloc((size_t)NEXP * 2048 * 4);
  int*   tk_e    = (int*)alloc((size_t)2 * T_TOK * 4);
  int*   tk_pos  = (int*)alloc((size_t)2 * T_TOK * 4);
  float* tk_prob = (float*)alloc((size_t)2 * T_TOK * 4);

  u16* src_bf  = (u16*)alloc((size_t)T_TOK * DMODEL * 2);
  u16* inw_bf  = (u16*)alloc((size_t)3 * DMODEL * DMODEL * 2);
  u16* outw_bf = (u16*)alloc((size_t)DMODEL * DMODEL * 2);
  u16* w1_bf   = (u16*)alloc((size_t)NEXP * FDIM * DMODEL * 2);
  u16* w2_bf   = (u16*)alloc((size_t)NEXP * DMODEL * FDIM * 2);
  u16* qkv_bf  = (u16*)alloc((size_t)T_TOK * 3 * DMODEL * 2);
  u16* vt_bf   = (u16*)alloc((size_t)T_TOK * DMODEL * 2);    // (B,H,HD,S)
  u16* o2_bf   = (u16*)alloc((size_t)T_TOK * DMODEL * 2);    // (B,S,D)
  float* attn_p= (float*)alloc((size_t)2 * T_TOK * DMODEL * 4);  // 2 split-K partials
  float* x_f   = (float*)alloc((size_t)T_TOK * DMODEL * 4);
  u16* x_bf    = (u16*)alloc((size_t)T_TOK * DMODEL * 2);
  u16* xg_bf   = (u16*)alloc((size_t)2 * T_TOK * DMODEL * 2);
  u16* h_bf    = (u16*)alloc((size_t)2 * T_TOK * FDIM * 2);
  float* y_f   = (float*)alloc((size_t)4 * T_TOK * DMODEL * 4);  // 2 K-halves
  (void)ws_size; (void)n_in; (void)in_sizes; (void)out_size;

  hipMemsetAsync(cnt, 0, 3 * 256, stream);  // cnt, offp, usage regions

  // bf16 conversions
  cvt_small<<<(T_TOK * DMODEL / 4 + 255) / 256, 256, 0, stream>>>(src, src_bf, T_TOK * DMODEL / 4);
  cvt_small<<<(3 * DMODEL * DMODEL / 4 + 255) / 256, 256, 0, stream>>>(inw, inw_bf, 3L * DMODEL * DMODEL / 4);
  cvt_small<<<(DMODEL * DMODEL / 4 + 255) / 256, 256, 0, stream>>>(outw, outw_bf, (long)DMODEL * DMODEL / 4);
  cvt_w1<<<(int)((long)NEXP * FDIM * DMODEL / 4 / 256), 256, 0, stream>>>(w1, w1_bf, (long)NEXP * FDIM * DMODEL / 4);
  cvt_w2<<<(int)((long)NEXP * DMODEL * FDIM / 4 / 256), 256, 0, stream>>>(w2, w2_bf, (long)NEXP * DMODEL * FDIM / 4);

  // QKV projection: (2048x1024) @ (3072x1024)^T + b -> bf16  (BM=128)
  k_qkv<<<dim3(24, 16), 256, 0, stream>>>(src_bf, inw_bf, qkv_bf, inb);

  transpose_v<<<dim3(16, 32), 256, 0, stream>>>(qkv_bf, vt_bf);

  // fused flash attention -> o2_bf (B,S,D)
  fused_attn<<<dim3(8, 32), 256, 0, stream>>>(qkv_bf, vt_bf, o2_bf);

  // output projection, split-K=2 -> two fp32 partials (bias folded into add_ln)
  k_outp<<<dim3(8, 32, 2), 256, 0, stream>>>(o2_bf, outw_bf, attn_p);

  // residual + out-proj bias + LN1
  add_ln<<<T_TOK, 256, 0, stream>>>(src, attn_p, attn_p + (long)T_TOK * DMODEL,
                                    outb, g1, bb1, x_f, x_bf);

  // gate + routing
  gate_kernel<<<T_TOK / 4, 256, 0, stream>>>(x_f, gw, gb, cnt, tok_list,
                                             tk_e, tk_pos, tk_prob, usage);
  finalize_gate<<<1, 64, 0, stream>>>(cnt, offp, usage, out + (long)T_TOK * DMODEL);

  gather_x<<<dim3(2048, 8), 256, 0, stream>>>(x_bf, cnt, offp, tok_list, xg_bf);

  // FFN1 (grouped, gelu fused) -> bf16
  k_ffn1<<<dim3(32, 16, 8), 256, 0, stream>>>(xg_bf, w1_bf, h_bf, b1, cnt, offp);

  // FFN2 (grouped, BM=128, split-K=2) -> 2 fp32 partial buffers
  k_ffn2<<<dim3(8, 16, 16), 256, 0, stream>>>(h_bf, w2_bf, y_f, cnt, offp);

  // combine (partials + b2) + residual + LN2 -> output
  moe_ln2<<<T_TOK, 256, 0, stream>>>(x_f, y_f, b2, offp, tk_e, tk_pos, tk_prob,
                                     g2, bb2, out);
}